// Round 9
// baseline (995.615 us; speedup 1.0000x reference)
//
#include <hip/hip_runtime.h>
#include <cstdint>

#define U64 unsigned long long

static constexpr int H = 38, W = 50, P = 1900;        // feature map
static constexpr int CIN = 2048, CMID = 256;
static constexpr int NA = 9, NBOX = 17100;            // 1900*9
static constexpr int HP = 40, WP = 52, QP = HP * WP;  // padded positions (2080)
static constexpr int TPITCH = 2084;                   // in_tT row pitch (floats), mult of 4
static constexpr int KS = 7;                          // split-K over cin
static constexpr int NW = 268;                        // u64 words covering NBOX bits
static constexpr int MSTRIDE = 272;                   // mask row stride (words)
static constexpr float NMS_T = 0.5f;
static constexpr int QTILE = 256;

// ---------------- ws layout (bytes) ----------------
static constexpr size_t SZ_INT  = (size_t)CIN * TPITCH * 4;   // 17,072,128
static constexpr size_t SZ_WT   = (size_t)9 * CIN * CMID * 4; // 18,874,368
static constexpr size_t SZ_PART = (size_t)KS * P * CMID * 4;  // 13,619,200
static constexpr size_t OFF_INT  = 0;
static constexpr size_t OFF_WT   = OFF_INT + SZ_INT;
static constexpr size_t OFF_PART = OFF_WT + SZ_WT;
static constexpr size_t REGA     = OFF_PART + SZ_PART;        // 49,565,696
// region A overlay (dead after k_reduce): mask + coalesced diag band
static constexpr size_t OFF_MASK = 0;                          // mask [NBOX][MSTRIDE] (37.2 MB)
static constexpr size_t SZ_MASK  = (size_t)NBOX * MSTRIDE * 8; // 37,209,600
static constexpr size_t OFF_DIAG = SZ_MASK;                    // diagA [NBOX] u64 (136.8 KB)
static constexpr size_t OFF_MID  = REGA;
static constexpr size_t OFF_FG   = OFF_MID + 1945600;
static constexpr size_t OFF_BOX  = OFF_FG + 68608;
static constexpr size_t OFF_SBOX = OFF_BOX + 273664;
static constexpr size_t OFF_SAREA= OFF_SBOX + 273664;
static constexpr size_t OFF_CNT  = OFF_SAREA + 68608;
static constexpr size_t WS_NEED  = OFF_CNT + 68608;            // ~52.26 MB (unchanged)

__device__ __forceinline__ U64 rdlane64(U64 v, int l) {
    unsigned lo = (unsigned)__builtin_amdgcn_readlane((int)(unsigned)(v & 0xffffffffull), l);
    unsigned hi = (unsigned)__builtin_amdgcn_readlane((int)(unsigned)(v >> 32), l);
    return ((U64)hi << 32) | (U64)lo;
}

// ---------------- kernels ----------------

__global__ __launch_bounds__(256) void k_sentinel(float* out, int n) {
    int i = blockIdx.x * 256 + threadIdx.x;
    if (i < n) out[i] = 1.2345678e8f;
}

// feature_map [CIN][H][W] -> in_tT [CIN][TPITCH] (padded image rows; memset first)
__global__ __launch_bounds__(256) void k_in_t(const float* __restrict__ fm, float* __restrict__ in_tT) {
    int idx = blockIdx.x * 256 + threadIdx.x;
    if (idx >= CIN * (H * W)) return;
    int ci = idx / (H * W), hw = idx - ci * (H * W);
    int h = hw / W, w = hw - h * W;
    in_tT[(size_t)ci * TPITCH + (h + 1) * WP + 1 + w] = fm[idx];
}

// conv_w [CMID][CIN][3][3] -> w2 [y(8)][sub(4)][ci(2048)][k(9)][c(8)]
__global__ __launch_bounds__(256) void k_w_t(const float* __restrict__ cw, float* __restrict__ w2) {
    int idx = blockIdx.x * 256 + threadIdx.x;
    if (idx >= CMID * CIN * 9) return;
    int co = idx / (CIN * 9);
    int rem = idx - co * (CIN * 9);
    int ci = rem / 9, k = rem - ci * 9;
    w2[((size_t)(co >> 3) * CIN + ci) * 72 + k * 8 + (co & 7)] = cw[idx];
}

// 3x3 conv, split-K. grid 504 = 9 qtiles x 8 cout-groups x 7 z (XCD-swizzled).
__global__ __launch_bounds__(256, 2) void k_conv(const float* __restrict__ in_tT,
                                                 const float* __restrict__ w2,
                                                 float* __restrict__ partial) {
    __shared__ float4 s_in4[16 * 104];   // 16 ci x 104 skewed quads (26.6 KB)
    int t = threadIdx.x;
    int lane = t & 63;
    int sub = __builtin_amdgcn_readfirstlane(t >> 6);   // wave-uniform SGPR

    int raw = blockIdx.x;
    int xcd = raw & 7, i0 = raw >> 3;
    int L = xcd * 63 + i0;          // 504 = 8*63, bijective
    int z = L / 72;
    int r0 = L - z * 72;
    int bx = r0 % 9, by = r0 / 9;
    int q0 = bx * QTILE;
    int cout0 = by * 32;
    int cin0 = (z <= 1) ? 304 * z : 608 + 288 * (z - 2);   // 304,304,288x5
    int cin1 = cin0 + ((z <= 1) ? 304 : 288);

    float acc[4][8];
#pragma unroll
    for (int j = 0; j < 4; ++j)
#pragma unroll
        for (int c = 0; c < 8; ++c) acc[j][c] = 0.f;

    const float* wbase = w2 + (size_t)(by * 4 + sub) * CIN * 72;

    for (int c0 = cin0; c0 < cin1; c0 += 16) {
        for (int idx = t; idx < 16 * 92; idx += 256) {
            int r = idx / 92, j = idx - r * 92;
            int qf = q0 - 56 + 4 * j;
            float4 v = make_float4(0.f, 0.f, 0.f, 0.f);
            if (qf >= 0 && qf <= 2080)
                v = *reinterpret_cast<const float4*>(in_tT + (size_t)(c0 + r) * TPITCH + qf);
            s_in4[r * 104 + j + (j >> 3)] = v;
        }
        __syncthreads();
#pragma unroll 1
        for (int r = 0; r < 16; ++r) {
            const float4* row4 = s_in4 + r * 104;
            const float4* w4 = reinterpret_cast<const float4*>(wbase + (size_t)(c0 + r) * 72);
#pragma unroll
            for (int dy = 0; dy < 3; ++dy) {
                int v0 = lane + 13 * dy;
                int v1 = v0 + 1, v2 = v0 + 2;
                float4 F0 = row4[v0 + (v0 >> 3)];
                float4 F1 = row4[v1 + (v1 >> 3)];
                float4 F2 = row4[v2 + (v2 >> 3)];
                float F[12] = {F0.x, F0.y, F0.z, F0.w, F1.x, F1.y, F1.z, F1.w,
                               F2.x, F2.y, F2.z, F2.w};
#pragma unroll
                for (int dxi = 0; dxi < 3; ++dxi) {
                    int k = dy * 3 + dxi;
                    float4 wa = w4[k * 2], wb = w4[k * 2 + 1];
                    float wv[8] = {wa.x, wa.y, wa.z, wa.w, wb.x, wb.y, wb.z, wb.w};
#pragma unroll
                    for (int jj = 0; jj < 4; ++jj) {
                        float iv = F[jj + dxi + 3];
#pragma unroll
                        for (int c = 0; c < 8; ++c) acc[jj][c] += iv * wv[c];
                    }
                }
            }
        }
        __syncthreads();
    }
    float* part = partial + (size_t)z * P * CMID;
#pragma unroll
    for (int jj = 0; jj < 4; ++jj) {
        int q = q0 + 4 * lane + jj;
        if (q < QP) {
            int hp = q / WP, wp_ = q - hp * WP;
            if (hp >= 1 && hp <= H && wp_ >= 1 && wp_ <= W) {
                int p = (hp - 1) * W + (wp_ - 1);
                float* dst = part + (size_t)p * CMID + cout0 + sub * 8;
                float4* d4 = reinterpret_cast<float4*>(dst);
                d4[0] = make_float4(acc[jj][0], acc[jj][1], acc[jj][2], acc[jj][3]);
                d4[1] = make_float4(acc[jj][4], acc[jj][5], acc[jj][6], acc[jj][7]);
            }
        }
    }
}

// sum partials + bias + relu -> mid [P][CMID]
__global__ __launch_bounds__(256) void k_reduce(const float* __restrict__ partial,
                                                const float* __restrict__ bias,
                                                float* __restrict__ mid) {
    int p = blockIdx.x, c = threadIdx.x;
    float s = bias[c];
    for (int ks = 0; ks < KS; ++ks) s += partial[(size_t)ks * P * CMID + (size_t)p * CMID + c];
    mid[(size_t)p * CMID + c] = fmaxf(s, 0.f);
}

// 1x1 heads + softmax + anchors + loc2bbox + clip. 16 positions per block (4 reps).
__global__ __launch_bounds__(256) void k_heads(const float* __restrict__ mid,
                                               const float* __restrict__ score_w,
                                               const float* __restrict__ score_b,
                                               const float* __restrict__ loc_w,
                                               const float* __restrict__ loc_b,
                                               float* __restrict__ score_out,
                                               float* __restrict__ loc_out,
                                               float* __restrict__ anch_out,
                                               float* __restrict__ fg,
                                               float* __restrict__ boxes) {
    __shared__ float wl[256][56];
    __shared__ float bias[56];
    __shared__ float dots[4][64];
    int t = threadIdx.x;
    for (int idx = t; idx < 18 * 256; idx += 256) {
        int c = idx >> 8, i = idx & 255;
        wl[i][c] = score_w[idx];
    }
    for (int idx = t; idx < 36 * 256; idx += 256) {
        int c = idx >> 8, i = idx & 255;
        wl[i][18 + c] = loc_w[idx];
    }
    if (t < 18) bias[t] = score_b[t];
    else if (t < 54) bias[t] = loc_b[t - 18];
    __syncthreads();

    int pl = t >> 6, c = t & 63;
    for (int rep = 0; rep < 4; ++rep) {
        int p = blockIdx.x * 16 + rep * 4 + pl;
        if (c < 54 && p < P) {
            float d = bias[c];
            const float4* mp = reinterpret_cast<const float4*>(mid + (size_t)p * CMID);
            for (int i4 = 0; i4 < 64; ++i4) {
                float4 m4 = mp[i4];
                int i = i4 * 4;
                d += m4.x * wl[i][c] + m4.y * wl[i + 1][c] + m4.z * wl[i + 2][c] + m4.w * wl[i + 3][c];
            }
            dots[pl][c] = d;
        }
        __syncthreads();
        if (c < NA && p < P) {
            int a = c;
            int idx = p * NA + a;
            float l0 = dots[pl][2 * a], l1 = dots[pl][2 * a + 1];
            float mx = fmaxf(l0, l1);
            float e0 = expf(l0 - mx), e1 = expf(l1 - mx);
            float den = e0 + e1;
            float s0 = e0 / den, s1 = e1 / den;
            score_out[(size_t)idx * 2 + 0] = s0;
            score_out[(size_t)idx * 2 + 1] = s1;
            fg[idx] = s1;
            float dx = dots[pl][18 + 4 * a + 0];
            float dy = dots[pl][18 + 4 * a + 1];
            float dw = dots[pl][18 + 4 * a + 2];
            float dh = dots[pl][18 + 4 * a + 3];
            loc_out[(size_t)idx * 4 + 0] = dx;
            loc_out[(size_t)idx * 4 + 1] = dy;
            loc_out[(size_t)idx * 4 + 2] = dw;
            loc_out[(size_t)idx * 4 + 3] = dh;
            int hh = p / W, ww = p % W;
            const double scales[3] = {8.0, 16.0, 32.0};
            const double ratios[3] = {0.5, 1.0, 2.0};
            double s = scales[a / 3], r = ratios[a % 3];
            double wb2 = 16.0 * s * sqrt(r);
            double hb = wb2 / r;
            double xmin = 8.0 - wb2 / 2.0, ymin = 8.0 - hb / 2.0;
            float b0 = (float)xmin, b1 = (float)ymin;
            float b2 = (float)(xmin + wb2), b3 = (float)(ymin + hb);
            float gx = (float)(ww * 16), gy = (float)(hh * 16);
            float a0 = gx + b0, a1 = gy + b1, a2 = gx + b2, a3 = gy + b3;
            anch_out[(size_t)idx * 4 + 0] = a0;
            anch_out[(size_t)idx * 4 + 1] = a1;
            anch_out[(size_t)idx * 4 + 2] = a2;
            anch_out[(size_t)idx * 4 + 3] = a3;
            float aw = a2 - a0, ah = a3 - a1;
            float cx = a0 + 0.5f * aw, cy = a1 + 0.5f * ah;
            float ncx = dx * aw + cx, ncy = dy * ah + cy;
            float nw = expf(dw) * aw, nh = expf(dh) * ah;
            float x1 = ncx - 0.5f * nw, y1 = ncy - 0.5f * nh;
            float x2 = ncx + 0.5f * nw, y2 = ncy + 0.5f * nh;
            x1 = fminf(fmaxf(x1, 0.f), (float)(W * 16));
            x2 = fminf(fmaxf(x2, 0.f), (float)(W * 16));
            y1 = fminf(fmaxf(y1, 0.f), (float)(H * 16));
            y2 = fminf(fmaxf(y2, 0.f), (float)(H * 16));
            float4* bp = reinterpret_cast<float4*>(boxes);
            bp[idx] = make_float4(x1, y1, x2, y2);
        }
        __syncthreads();
    }
}

// partial stable-descending rank counts over a j-slice. grid (67, 8)
static constexpr int JSL = 2144;  // slice size (mult of 4)
__global__ __launch_bounds__(256) void k_rank_part(const float* __restrict__ fg,
                                                   int* __restrict__ cntb) {
    __shared__ float4 tile[256];
    int t = threadIdx.x;
    int i = blockIdx.x * 256 + t;
    int j0 = blockIdx.y * JSL;
    int j1 = min(NBOX, j0 + JSL);
    float my = (i < NBOX) ? fg[i] : 0.f;
    int cnt = 0;
    for (int base = j0; base < j1; base += 1024) {
        int j = base + t * 4;
        float4 v = make_float4(-3.4e38f, -3.4e38f, -3.4e38f, -3.4e38f);
        if (j + 3 < j1) {
            v = *reinterpret_cast<const float4*>(fg + j);
        } else {
            if (j < j1) v.x = fg[j];
            if (j + 1 < j1) v.y = fg[j + 1];
            if (j + 2 < j1) v.z = fg[j + 2];
            if (j + 3 < j1) v.w = fg[j + 3];
        }
        __syncthreads();
        tile[t] = v;
        __syncthreads();
        if (i < NBOX) {
            for (int u = 0; u < 256; ++u) {
                float4 s = tile[u];
                int jb = base + u * 4;
                cnt += (s.x > my) || (s.x == my && jb < i);
                cnt += (s.y > my) || (s.y == my && jb + 1 < i);
                cnt += (s.z > my) || (s.z == my && jb + 2 < i);
                cnt += (s.w > my) || (s.w == my && jb + 3 < i);
            }
        }
    }
    if (i < NBOX && cnt) atomicAdd(&cntb[i], cnt);
}

// scatter boxes to sorted order using rank counts
__global__ __launch_bounds__(256) void k_scatter(const int* __restrict__ cntb,
                                                 const float* __restrict__ boxes,
                                                 float* __restrict__ sboxes,
                                                 float* __restrict__ sarea) {
    int i = blockIdx.x * 256 + threadIdx.x;
    if (i >= NBOX) return;
    int c = cntb[i];
    float4 b = reinterpret_cast<const float4*>(boxes)[i];
    reinterpret_cast<float4*>(sboxes)[c] = b;
    sarea[c] = (b.z - b.x) * (b.w - b.y);
}

// NMS pair bitmask, row-major + coalesced diag band.
__global__ __launch_bounds__(256) void k_maskfill(const float* __restrict__ sboxes,
                                                  const float* __restrict__ sarea,
                                                  U64* __restrict__ mask,
                                                  U64* __restrict__ diagA) {
    int w = blockIdx.y;
    int i0 = blockIdx.x * 256;
    if (w < (i0 >> 6)) return;
    __shared__ float4 sb[64];
    __shared__ float sa[64];
    int t = threadIdx.x;
    if (t < 64) {
        int j = w * 64 + t;
        if (j < NBOX) {
            sb[t] = reinterpret_cast<const float4*>(sboxes)[j];
            sa[t] = sarea[j];
        } else {
            sb[t] = make_float4(0.f, 0.f, 0.f, 0.f);
            sa[t] = 0.f;
        }
    }
    __syncthreads();
    int i = i0 + t;
    if (i >= NBOX || w < (i >> 6)) return;
    float4 bi = reinterpret_cast<const float4*>(sboxes)[i];
    float ai = sarea[i];
    U64 word = 0;
#pragma unroll 4
    for (int jb = 0; jb < 64; ++jb) {
        int j = w * 64 + jb;
        float4 bj = sb[jb];
        float xx1 = fmaxf(bi.x, bj.x), yy1 = fmaxf(bi.y, bj.y);
        float xx2 = fminf(bi.z, bj.z), yy2 = fminf(bi.w, bj.w);
        float inter = fmaxf(xx2 - xx1, 0.f) * fmaxf(yy2 - yy1, 0.f);
        float iou = inter / (ai + sa[jb] - inter);
        word |= ((U64)((iou > NMS_T) && (j > i))) << jb;
    }
    mask[(size_t)i * MSTRIDE + w] = word;
    if (w == (i >> 6)) diagA[i] = word;
}

// exact greedy sweep v6: SINGLE WAVE, zero barriers, zero LDS.
// rem[268] lives in 5 per-lane registers (word w owned by lane w%64, reg w/64).
// Per round: readlane rem[g] -> kept-only resolve (diag band, depth-2 prefetch)
// -> outputs -> far-OR via batched coalesced row loads OR'd into registers.
__global__ __launch_bounds__(64) void k_sweep(const U64* __restrict__ mask,
                                              const U64* __restrict__ diagA,
                                              const float* __restrict__ sboxes,
                                              float* __restrict__ rois_out,
                                              float* __restrict__ keep_out) {
    int lane = threadIdx.x;
    U64 m0 = 0, m1 = 0, m2 = 0, m3 = 0, m4 = 0;
    unsigned base = 0;
    U64 dA = diagA[lane];        // group 0 diag (coalesced)
    U64 dB = diagA[64 + lane];   // group 1 diag

    auto step = [&](int g, U64& dR) {
        int gl = g & 63, gi = g >> 6;
        U64 mcur = (gi == 0) ? rdlane64(m0, gl)
                 : (gi == 1) ? rdlane64(m1, gl)
                 : (gi == 2) ? rdlane64(m2, gl)
                 : (gi == 3) ? rdlane64(m3, gl)
                             : rdlane64(m4, gl);
        int nv = min(64, NBOX - g * 64);
        U64 vmask = (nv == 64) ? ~0ull : ((1ull << nv) - 1);
        U64 notsup = ~mcur & vmask;
        U64 kept = 0;
        while (notsup) {
            int i = (int)__builtin_ctzll(notsup);
            kept |= (1ull << i);
            U64 wi = rdlane64(dR, i);
            notsup &= ~(wi | (1ull << i));
        }
        int nk = __popcll(kept);
        bool mine = (kept >> lane) & 1ull;
        if (mine) {
            unsigned pre = (unsigned)__popcll(kept & ((1ull << lane) - 1));
            unsigned dst = base + pre;
            float4 bb = reinterpret_cast<const float4*>(sboxes)[g * 64 + lane];
            reinterpret_cast<float4*>(rois_out)[dst] = bb;
            keep_out[dst] = 1.0f;
        }
        base += (unsigned)nk;

        // far-OR: batches of <=4 kept rows; coalesced loads, one waitcnt per batch
        U64 kk = kept;
        while (kk) {
            int i0 = (int)__builtin_ctzll(kk); kk &= kk - 1;
            int i1 = i0, i2 = i0, i3 = i0;
            if (kk) { i1 = (int)__builtin_ctzll(kk); kk &= kk - 1;
                if (kk) { i2 = (int)__builtin_ctzll(kk); kk &= kk - 1;
                    if (kk) { i3 = (int)__builtin_ctzll(kk); kk &= kk - 1; } } }
            const U64* p0 = mask + (size_t)(g * 64 + i0) * MSTRIDE;
            const U64* p1 = mask + (size_t)(g * 64 + i1) * MSTRIDE;
            const U64* p2 = mask + (size_t)(g * 64 + i2) * MSTRIDE;
            const U64* p3 = mask + (size_t)(g * 64 + i3) * MSTRIDE;
            int w0 = lane, w1 = 64 + lane, w2 = 128 + lane, w3 = 192 + lane, w4 = 256 + lane;
            if (w0 > g) m0 |= p0[w0] | p1[w0] | p2[w0] | p3[w0];
            if (w1 > g) m1 |= p0[w1] | p1[w1] | p2[w1] | p3[w1];
            if (w2 > g) m2 |= p0[w2] | p1[w2] | p2[w2] | p3[w2];
            if (w3 > g) m3 |= p0[w3] | p1[w3] | p2[w3] | p3[w3];
            if (w4 > g && w4 < NW) m4 |= p0[w4] | p1[w4] | p2[w4] | p3[w4];
        }

        // refill diag prefetch for group g+2 (coalesced; consumed 2 rounds later)
        int r2 = (g + 2) * 64 + lane;
        dR = (g + 2 < NW && r2 < NBOX) ? diagA[r2] : 0;
    };

    for (int g = 0; g < NW; g += 2) {   // NW even
        step(g, dA);
        step(g + 1, dB);
    }
}

// ---------------- launch ----------------
extern "C" void kernel_launch(void* const* d_in, const int* in_sizes, int n_in,
                              void* d_out, int out_size, void* d_ws, size_t ws_size,
                              hipStream_t stream) {
    const float* fm      = (const float*)d_in[0];
    const float* conv_w  = (const float*)d_in[2];
    const float* conv_b  = (const float*)d_in[3];
    const float* score_w = (const float*)d_in[4];
    const float* score_b = (const float*)d_in[5];
    const float* loc_w   = (const float*)d_in[6];
    const float* loc_b   = (const float*)d_in[7];

    float* out = (float*)d_out;
    float* rois_out  = out;
    float* keep_out  = out + NBOX * 4;
    float* anch_out  = out + NBOX * 5;
    float* loc_out   = out + NBOX * 9;
    float* score_out = out + NBOX * 13;

    if (ws_size < WS_NEED) {
        k_sentinel<<<(out_size + 255) / 256, 256, 0, stream>>>(out, out_size);
        return;
    }

    char* ws = (char*)d_ws;
    float* in_tT   = (float*)(ws + OFF_INT);
    float* w2      = (float*)(ws + OFF_WT);
    float* partial = (float*)(ws + OFF_PART);
    U64*   mask    = (U64*)(ws + OFF_MASK);
    U64*   diagA   = (U64*)(ws + OFF_DIAG);
    float* mid     = (float*)(ws + OFF_MID);
    float* fg      = (float*)(ws + OFF_FG);
    float* boxes   = (float*)(ws + OFF_BOX);
    float* sboxes  = (float*)(ws + OFF_SBOX);
    float* sarea   = (float*)(ws + OFF_SAREA);
    int*   cntb    = (int*)(ws + OFF_CNT);

    hipMemsetAsync(in_tT, 0, SZ_INT, stream);
    k_in_t<<<(CIN * H * W + 255) / 256, 256, 0, stream>>>(fm, in_tT);
    k_w_t<<<(CMID * CIN * 9 + 255) / 256, 256, 0, stream>>>(conv_w, w2);
    k_conv<<<504, 256, 0, stream>>>(in_tT, w2, partial);
    k_reduce<<<P, 256, 0, stream>>>(partial, conv_b, mid);
    k_heads<<<(P + 15) / 16, 256, 0, stream>>>(mid, score_w, score_b, loc_w, loc_b,
                                               score_out, loc_out, anch_out, fg, boxes);
    hipMemsetAsync(cntb, 0, NBOX * 4, stream);
    k_rank_part<<<dim3((NBOX + 255) / 256, 8), 256, 0, stream>>>(fg, cntb);
    k_scatter<<<(NBOX + 255) / 256, 256, 0, stream>>>(cntb, boxes, sboxes, sarea);
    hipMemsetAsync(rois_out, 0, (size_t)NBOX * 5 * 4, stream);  // rois_out + keep
    k_maskfill<<<dim3((NBOX + 255) / 256, NW), 256, 0, stream>>>(sboxes, sarea, mask, diagA);
    k_sweep<<<1, 64, 0, stream>>>(mask, diagA, sboxes, rois_out, keep_out);
}

// Round 10
// 937.920 us; speedup vs baseline: 1.0615x; 1.0615x over previous
//
#include <hip/hip_runtime.h>
#include <cstdint>

#define U64 unsigned long long

static constexpr int H = 38, W = 50, P = 1900;        // feature map
static constexpr int CIN = 2048, CMID = 256;
static constexpr int NA = 9, NBOX = 17100;            // 1900*9
static constexpr int HP = 40, WP = 52, QP = HP * WP;  // padded positions (2080)
static constexpr int TPITCH = 2084;                   // in_tT row pitch (floats), mult of 4
static constexpr int KS = 7;                          // split-K over cin
static constexpr int NW = 268;                        // u64 words covering NBOX bits
static constexpr int MSTRIDE = 272;                   // mask row stride (words)
static constexpr int NG = 67;                         // 256-box groups
static constexpr float NMS_T = 0.5f;
static constexpr int QTILE = 256;

// ---------------- ws layout (bytes) ----------------
static constexpr size_t SZ_INT  = (size_t)CIN * TPITCH * 4;   // 17,072,128
static constexpr size_t SZ_WT   = (size_t)9 * CIN * CMID * 4; // 18,874,368
static constexpr size_t SZ_PART = (size_t)KS * P * CMID * 4;  // 13,619,200
static constexpr size_t OFF_INT  = 0;
static constexpr size_t OFF_WT   = OFF_INT + SZ_INT;
static constexpr size_t OFF_PART = OFF_WT + SZ_WT;
static constexpr size_t REGA     = OFF_PART + SZ_PART;        // 49,565,696
// region A overlay (dead after k_reduce): mask + diag 256-blocks
static constexpr size_t OFF_MASK = 0;                          // mask [NBOX][MSTRIDE] (37.2 MB)
static constexpr size_t SZ_MASK  = (size_t)NBOX * MSTRIDE * 8; // 37,209,600
static constexpr size_t OFF_DIAG = SZ_MASK;                    // diagX [67][4][4][64] u64 (549 KB)
static constexpr size_t SZ_DIAG  = (size_t)NG * 1024 * 8;      // 548,864
static constexpr size_t OFF_MID  = REGA;
static constexpr size_t OFF_FG   = OFF_MID + 1945600;
static constexpr size_t OFF_BOX  = OFF_FG + 68608;
static constexpr size_t OFF_SBOX = OFF_BOX + 273664;
static constexpr size_t OFF_SAREA= OFF_SBOX + 273664;
static constexpr size_t OFF_CNT  = OFF_SAREA + 68608;
static constexpr size_t WS_NEED  = OFF_CNT + 68608;            // ~52.26 MB (unchanged)

__device__ __forceinline__ U64 rdlane64(U64 v, int l) {
    unsigned lo = (unsigned)__builtin_amdgcn_readlane((int)(unsigned)(v & 0xffffffffull), l);
    unsigned hi = (unsigned)__builtin_amdgcn_readlane((int)(unsigned)(v >> 32), l);
    return ((U64)hi << 32) | (U64)lo;
}

__device__ __forceinline__ U64 vmaskw(int wg) {
    int rem = NBOX - wg * 64;
    if (rem >= 64) return ~0ull;
    if (rem <= 0) return 0ull;
    return (1ull << rem) - 1ull;
}

// ---------------- kernels ----------------

__global__ __launch_bounds__(256) void k_sentinel(float* out, int n) {
    int i = blockIdx.x * 256 + threadIdx.x;
    if (i < n) out[i] = 1.2345678e8f;
}

// feature_map [CIN][H][W] -> in_tT [CIN][TPITCH] (padded image rows; memset first)
__global__ __launch_bounds__(256) void k_in_t(const float* __restrict__ fm, float* __restrict__ in_tT) {
    int idx = blockIdx.x * 256 + threadIdx.x;
    if (idx >= CIN * (H * W)) return;
    int ci = idx / (H * W), hw = idx - ci * (H * W);
    int h = hw / W, w = hw - h * W;
    in_tT[(size_t)ci * TPITCH + (h + 1) * WP + 1 + w] = fm[idx];
}

// conv_w [CMID][CIN][3][3] -> w2 [y(8)][sub(4)][ci(2048)][k(9)][c(8)]
__global__ __launch_bounds__(256) void k_w_t(const float* __restrict__ cw, float* __restrict__ w2) {
    int idx = blockIdx.x * 256 + threadIdx.x;
    if (idx >= CMID * CIN * 9) return;
    int co = idx / (CIN * 9);
    int rem = idx - co * (CIN * 9);
    int ci = rem / 9, k = rem - ci * 9;
    w2[((size_t)(co >> 3) * CIN + ci) * 72 + k * 8 + (co & 7)] = cw[idx];
}

// 3x3 conv, split-K. grid 504 = 9 qtiles x 8 cout-groups x 7 z (XCD-swizzled).
__global__ __launch_bounds__(256, 2) void k_conv(const float* __restrict__ in_tT,
                                                 const float* __restrict__ w2,
                                                 float* __restrict__ partial) {
    __shared__ float4 s_in4[16 * 104];   // 16 ci x 104 skewed quads (26.6 KB)
    int t = threadIdx.x;
    int lane = t & 63;
    int sub = __builtin_amdgcn_readfirstlane(t >> 6);   // wave-uniform SGPR

    int raw = blockIdx.x;
    int xcd = raw & 7, i0 = raw >> 3;
    int L = xcd * 63 + i0;          // 504 = 8*63, bijective
    int z = L / 72;
    int r0 = L - z * 72;
    int bx = r0 % 9, by = r0 / 9;
    int q0 = bx * QTILE;
    int cout0 = by * 32;
    int cin0 = (z <= 1) ? 304 * z : 608 + 288 * (z - 2);   // 304,304,288x5
    int cin1 = cin0 + ((z <= 1) ? 304 : 288);

    float acc[4][8];
#pragma unroll
    for (int j = 0; j < 4; ++j)
#pragma unroll
        for (int c = 0; c < 8; ++c) acc[j][c] = 0.f;

    const float* wbase = w2 + (size_t)(by * 4 + sub) * CIN * 72;

    for (int c0 = cin0; c0 < cin1; c0 += 16) {
        for (int idx = t; idx < 16 * 92; idx += 256) {
            int r = idx / 92, j = idx - r * 92;
            int qf = q0 - 56 + 4 * j;
            float4 v = make_float4(0.f, 0.f, 0.f, 0.f);
            if (qf >= 0 && qf <= 2080)
                v = *reinterpret_cast<const float4*>(in_tT + (size_t)(c0 + r) * TPITCH + qf);
            s_in4[r * 104 + j + (j >> 3)] = v;
        }
        __syncthreads();
#pragma unroll 1
        for (int r = 0; r < 16; ++r) {
            const float4* row4 = s_in4 + r * 104;
            const float4* w4 = reinterpret_cast<const float4*>(wbase + (size_t)(c0 + r) * 72);
#pragma unroll
            for (int dy = 0; dy < 3; ++dy) {
                int v0 = lane + 13 * dy;
                int v1 = v0 + 1, v2 = v0 + 2;
                float4 F0 = row4[v0 + (v0 >> 3)];
                float4 F1 = row4[v1 + (v1 >> 3)];
                float4 F2 = row4[v2 + (v2 >> 3)];
                float F[12] = {F0.x, F0.y, F0.z, F0.w, F1.x, F1.y, F1.z, F1.w,
                               F2.x, F2.y, F2.z, F2.w};
#pragma unroll
                for (int dxi = 0; dxi < 3; ++dxi) {
                    int k = dy * 3 + dxi;
                    float4 wa = w4[k * 2], wb = w4[k * 2 + 1];
                    float wv[8] = {wa.x, wa.y, wa.z, wa.w, wb.x, wb.y, wb.z, wb.w};
#pragma unroll
                    for (int jj = 0; jj < 4; ++jj) {
                        float iv = F[jj + dxi + 3];
#pragma unroll
                        for (int c = 0; c < 8; ++c) acc[jj][c] += iv * wv[c];
                    }
                }
            }
        }
        __syncthreads();
    }
    float* part = partial + (size_t)z * P * CMID;
#pragma unroll
    for (int jj = 0; jj < 4; ++jj) {
        int q = q0 + 4 * lane + jj;
        if (q < QP) {
            int hp = q / WP, wp_ = q - hp * WP;
            if (hp >= 1 && hp <= H && wp_ >= 1 && wp_ <= W) {
                int p = (hp - 1) * W + (wp_ - 1);
                float* dst = part + (size_t)p * CMID + cout0 + sub * 8;
                float4* d4 = reinterpret_cast<float4*>(dst);
                d4[0] = make_float4(acc[jj][0], acc[jj][1], acc[jj][2], acc[jj][3]);
                d4[1] = make_float4(acc[jj][4], acc[jj][5], acc[jj][6], acc[jj][7]);
            }
        }
    }
}

// sum partials + bias + relu -> mid [P][CMID]
__global__ __launch_bounds__(256) void k_reduce(const float* __restrict__ partial,
                                                const float* __restrict__ bias,
                                                float* __restrict__ mid) {
    int p = blockIdx.x, c = threadIdx.x;
    float s = bias[c];
    for (int ks = 0; ks < KS; ++ks) s += partial[(size_t)ks * P * CMID + (size_t)p * CMID + c];
    mid[(size_t)p * CMID + c] = fmaxf(s, 0.f);
}

// 1x1 heads + softmax + anchors + loc2bbox + clip. 16 positions per block (4 reps).
__global__ __launch_bounds__(256) void k_heads(const float* __restrict__ mid,
                                               const float* __restrict__ score_w,
                                               const float* __restrict__ score_b,
                                               const float* __restrict__ loc_w,
                                               const float* __restrict__ loc_b,
                                               float* __restrict__ score_out,
                                               float* __restrict__ loc_out,
                                               float* __restrict__ anch_out,
                                               float* __restrict__ fg,
                                               float* __restrict__ boxes) {
    __shared__ float wl[256][56];
    __shared__ float bias[56];
    __shared__ float dots[4][64];
    int t = threadIdx.x;
    for (int idx = t; idx < 18 * 256; idx += 256) {
        int c = idx >> 8, i = idx & 255;
        wl[i][c] = score_w[idx];
    }
    for (int idx = t; idx < 36 * 256; idx += 256) {
        int c = idx >> 8, i = idx & 255;
        wl[i][18 + c] = loc_w[idx];
    }
    if (t < 18) bias[t] = score_b[t];
    else if (t < 54) bias[t] = loc_b[t - 18];
    __syncthreads();

    int pl = t >> 6, c = t & 63;
    for (int rep = 0; rep < 4; ++rep) {
        int p = blockIdx.x * 16 + rep * 4 + pl;
        if (c < 54 && p < P) {
            float d = bias[c];
            const float4* mp = reinterpret_cast<const float4*>(mid + (size_t)p * CMID);
            for (int i4 = 0; i4 < 64; ++i4) {
                float4 m4 = mp[i4];
                int i = i4 * 4;
                d += m4.x * wl[i][c] + m4.y * wl[i + 1][c] + m4.z * wl[i + 2][c] + m4.w * wl[i + 3][c];
            }
            dots[pl][c] = d;
        }
        __syncthreads();
        if (c < NA && p < P) {
            int a = c;
            int idx = p * NA + a;
            float l0 = dots[pl][2 * a], l1 = dots[pl][2 * a + 1];
            float mx = fmaxf(l0, l1);
            float e0 = expf(l0 - mx), e1 = expf(l1 - mx);
            float den = e0 + e1;
            float s0 = e0 / den, s1 = e1 / den;
            score_out[(size_t)idx * 2 + 0] = s0;
            score_out[(size_t)idx * 2 + 1] = s1;
            fg[idx] = s1;
            float dx = dots[pl][18 + 4 * a + 0];
            float dy = dots[pl][18 + 4 * a + 1];
            float dw = dots[pl][18 + 4 * a + 2];
            float dh = dots[pl][18 + 4 * a + 3];
            loc_out[(size_t)idx * 4 + 0] = dx;
            loc_out[(size_t)idx * 4 + 1] = dy;
            loc_out[(size_t)idx * 4 + 2] = dw;
            loc_out[(size_t)idx * 4 + 3] = dh;
            int hh = p / W, ww = p % W;
            const double scales[3] = {8.0, 16.0, 32.0};
            const double ratios[3] = {0.5, 1.0, 2.0};
            double s = scales[a / 3], r = ratios[a % 3];
            double wb2 = 16.0 * s * sqrt(r);
            double hb = wb2 / r;
            double xmin = 8.0 - wb2 / 2.0, ymin = 8.0 - hb / 2.0;
            float b0 = (float)xmin, b1 = (float)ymin;
            float b2 = (float)(xmin + wb2), b3 = (float)(ymin + hb);
            float gx = (float)(ww * 16), gy = (float)(hh * 16);
            float a0 = gx + b0, a1 = gy + b1, a2 = gx + b2, a3 = gy + b3;
            anch_out[(size_t)idx * 4 + 0] = a0;
            anch_out[(size_t)idx * 4 + 1] = a1;
            anch_out[(size_t)idx * 4 + 2] = a2;
            anch_out[(size_t)idx * 4 + 3] = a3;
            float aw = a2 - a0, ah = a3 - a1;
            float cx = a0 + 0.5f * aw, cy = a1 + 0.5f * ah;
            float ncx = dx * aw + cx, ncy = dy * ah + cy;
            float nw = expf(dw) * aw, nh = expf(dh) * ah;
            float x1 = ncx - 0.5f * nw, y1 = ncy - 0.5f * nh;
            float x2 = ncx + 0.5f * nw, y2 = ncy + 0.5f * nh;
            x1 = fminf(fmaxf(x1, 0.f), (float)(W * 16));
            x2 = fminf(fmaxf(x2, 0.f), (float)(W * 16));
            y1 = fminf(fmaxf(y1, 0.f), (float)(H * 16));
            y2 = fminf(fmaxf(y2, 0.f), (float)(H * 16));
            float4* bp = reinterpret_cast<float4*>(boxes);
            bp[idx] = make_float4(x1, y1, x2, y2);
        }
        __syncthreads();
    }
}

// partial stable-descending rank counts over a j-slice. grid (67, 8)
static constexpr int JSL = 2144;  // slice size (mult of 4)
__global__ __launch_bounds__(256) void k_rank_part(const float* __restrict__ fg,
                                                   int* __restrict__ cntb) {
    __shared__ float4 tile[256];
    int t = threadIdx.x;
    int i = blockIdx.x * 256 + t;
    int j0 = blockIdx.y * JSL;
    int j1 = min(NBOX, j0 + JSL);
    float my = (i < NBOX) ? fg[i] : 0.f;
    int cnt = 0;
    for (int base = j0; base < j1; base += 1024) {
        int j = base + t * 4;
        float4 v = make_float4(-3.4e38f, -3.4e38f, -3.4e38f, -3.4e38f);
        if (j + 3 < j1) {
            v = *reinterpret_cast<const float4*>(fg + j);
        } else {
            if (j < j1) v.x = fg[j];
            if (j + 1 < j1) v.y = fg[j + 1];
            if (j + 2 < j1) v.z = fg[j + 2];
            if (j + 3 < j1) v.w = fg[j + 3];
        }
        __syncthreads();
        tile[t] = v;
        __syncthreads();
        if (i < NBOX) {
            for (int u = 0; u < 256; ++u) {
                float4 s = tile[u];
                int jb = base + u * 4;
                cnt += (s.x > my) || (s.x == my && jb < i);
                cnt += (s.y > my) || (s.y == my && jb + 1 < i);
                cnt += (s.z > my) || (s.z == my && jb + 2 < i);
                cnt += (s.w > my) || (s.w == my && jb + 3 < i);
            }
        }
    }
    if (i < NBOX && cnt) atomicAdd(&cntb[i], cnt);
}

// scatter boxes to sorted order using rank counts
__global__ __launch_bounds__(256) void k_scatter(const int* __restrict__ cntb,
                                                 const float* __restrict__ boxes,
                                                 float* __restrict__ sboxes,
                                                 float* __restrict__ sarea) {
    int i = blockIdx.x * 256 + threadIdx.x;
    if (i >= NBOX) return;
    int c = cntb[i];
    float4 b = reinterpret_cast<const float4*>(boxes)[i];
    reinterpret_cast<float4*>(sboxes)[c] = b;
    sarea[c] = (b.z - b.x) * (b.w - b.y);
}

// NMS pair bitmask, row-major + diag 256-block bands (diagX memset 0 first).
__global__ __launch_bounds__(256) void k_maskfill(const float* __restrict__ sboxes,
                                                  const float* __restrict__ sarea,
                                                  U64* __restrict__ mask,
                                                  U64* __restrict__ diagX) {
    int w = blockIdx.y;
    int i0 = blockIdx.x * 256;
    if (w < (i0 >> 6)) return;
    __shared__ float4 sb[64];
    __shared__ float sa[64];
    int t = threadIdx.x;
    if (t < 64) {
        int j = w * 64 + t;
        if (j < NBOX) {
            sb[t] = reinterpret_cast<const float4*>(sboxes)[j];
            sa[t] = sarea[j];
        } else {
            sb[t] = make_float4(0.f, 0.f, 0.f, 0.f);
            sa[t] = 0.f;
        }
    }
    __syncthreads();
    int i = i0 + t;
    if (i >= NBOX || w < (i >> 6)) return;
    float4 bi = reinterpret_cast<const float4*>(sboxes)[i];
    float ai = sarea[i];
    U64 word = 0;
#pragma unroll 4
    for (int jb = 0; jb < 64; ++jb) {
        int j = w * 64 + jb;
        float4 bj = sb[jb];
        float xx1 = fmaxf(bi.x, bj.x), yy1 = fmaxf(bi.y, bj.y);
        float xx2 = fminf(bi.z, bj.z), yy2 = fminf(bi.w, bj.w);
        float inter = fmaxf(xx2 - xx1, 0.f) * fmaxf(yy2 - yy1, 0.f);
        float iou = inter / (ai + sa[jb] - inter);
        word |= ((U64)((iou > NMS_T) && (j > i))) << jb;
    }
    mask[(size_t)i * MSTRIDE + w] = word;
    int gi = i >> 8;
    int wl = w - gi * 4;
    if (wl >= 0 && wl < 4)
        diagX[(size_t)gi * 1024 + wl * 256 + (i & 255)] = word;
}

// ---- sweep v7: single wave, G=256 groups (67 rounds), depth-1 diag prefetch,
//      4 independent far-OR accumulator sets (16 rows / 80 loads in flight).
#define DVARS(P) U64 P##00, P##01, P##02, P##03, P##10, P##11, P##12, P##13, \
                     P##20, P##21, P##22, P##23, P##30, P##31, P##32, P##33

#define LOADD(P, G) do { \
    const U64* _dp = diagX + (size_t)(G) * 1024 + lane; \
    P##00 = _dp[0];   P##01 = _dp[64];  P##02 = _dp[128]; P##03 = _dp[192]; \
    P##10 = _dp[256]; P##11 = _dp[320]; P##12 = _dp[384]; P##13 = _dp[448]; \
    P##20 = _dp[512]; P##21 = _dp[576]; P##22 = _dp[640]; P##23 = _dp[704]; \
    P##30 = _dp[768]; P##31 = _dp[832]; P##32 = _dp[896]; P##33 = _dp[960]; \
} while (0)

#define ZEROD(P) do { \
    P##00 = P##01 = P##02 = P##03 = P##10 = P##11 = P##12 = P##13 = 0; \
    P##20 = P##21 = P##22 = P##23 = P##30 = P##31 = P##32 = P##33 = 0; \
} while (0)

#define POPR(R) \
    int R; \
    do { \
        if (kk0) { int _i = (int)__builtin_ctzll(kk0); kk0 &= kk0 - 1; R = _i; } \
        else if (kk1) { int _i = (int)__builtin_ctzll(kk1); kk1 &= kk1 - 1; R = 64 + _i; } \
        else if (kk2) { int _i = (int)__builtin_ctzll(kk2); kk2 &= kk2 - 1; R = 128 + _i; } \
        else if (kk3) { int _i = (int)__builtin_ctzll(kk3); kk3 &= kk3 - 1; R = 192 + _i; } \
        else R = -1; \
    } while (0)

#define STEP(G, DU, DN) do { \
    const int g_ = (G); \
    if (g_ + 1 < NG) { LOADD(DN, g_ + 1); } else { ZEROD(DN); } \
    const int gbase = g_ * 256; \
    int rsel = g_ >> 4; \
    U64 msel = (rsel == 0) ? m0 : (rsel == 1) ? m1 : (rsel == 2) ? m2 : (rsel == 3) ? m3 : m4; \
    int lb = (g_ * 4) & 63; \
    U64 mc0 = rdlane64(msel, lb), mc1 = rdlane64(msel, lb + 1); \
    U64 mc2 = rdlane64(msel, lb + 2), mc3 = rdlane64(msel, lb + 3); \
    U64 ns0 = ~mc0 & vmaskw(g_ * 4),     ns1 = ~mc1 & vmaskw(g_ * 4 + 1); \
    U64 ns2 = ~mc2 & vmaskw(g_ * 4 + 2), ns3 = ~mc3 & vmaskw(g_ * 4 + 3); \
    U64 k0 = 0, k1 = 0, k2 = 0, k3 = 0; \
    while (ns0) { \
        int i = (int)__builtin_ctzll(ns0); \
        k0 |= 1ull << i; \
        ns0 &= ~(rdlane64(DU##00, i) | (1ull << i)); \
        ns1 &= ~rdlane64(DU##10, i); \
        ns2 &= ~rdlane64(DU##20, i); \
        ns3 &= ~rdlane64(DU##30, i); \
    } \
    while (ns1) { \
        int i = (int)__builtin_ctzll(ns1); \
        k1 |= 1ull << i; \
        ns1 &= ~(rdlane64(DU##11, i) | (1ull << i)); \
        ns2 &= ~rdlane64(DU##21, i); \
        ns3 &= ~rdlane64(DU##31, i); \
    } \
    while (ns2) { \
        int i = (int)__builtin_ctzll(ns2); \
        k2 |= 1ull << i; \
        ns2 &= ~(rdlane64(DU##22, i) | (1ull << i)); \
        ns3 &= ~rdlane64(DU##32, i); \
    } \
    while (ns3) { \
        int i = (int)__builtin_ctzll(ns3); \
        k3 |= 1ull << i; \
        ns3 &= ~(rdlane64(DU##33, i) | (1ull << i)); \
    } \
    unsigned c0 = (unsigned)__popcll(k0), c1 = (unsigned)__popcll(k1); \
    unsigned c2 = (unsigned)__popcll(k2), c3 = (unsigned)__popcll(k3); \
    U64 lmask = (1ull << lane) - 1ull; \
    if ((k0 >> lane) & 1) { \
        unsigned dst = base + (unsigned)__popcll(k0 & lmask); \
        reinterpret_cast<float4*>(rois_out)[dst] = reinterpret_cast<const float4*>(sboxes)[gbase + lane]; \
        keep_out[dst] = 1.0f; \
    } \
    if ((k1 >> lane) & 1) { \
        unsigned dst = base + c0 + (unsigned)__popcll(k1 & lmask); \
        reinterpret_cast<float4*>(rois_out)[dst] = reinterpret_cast<const float4*>(sboxes)[gbase + 64 + lane]; \
        keep_out[dst] = 1.0f; \
    } \
    if ((k2 >> lane) & 1) { \
        unsigned dst = base + c0 + c1 + (unsigned)__popcll(k2 & lmask); \
        reinterpret_cast<float4*>(rois_out)[dst] = reinterpret_cast<const float4*>(sboxes)[gbase + 128 + lane]; \
        keep_out[dst] = 1.0f; \
    } \
    if ((k3 >> lane) & 1) { \
        unsigned dst = base + c0 + c1 + c2 + (unsigned)__popcll(k3 & lmask); \
        reinterpret_cast<float4*>(rois_out)[dst] = reinterpret_cast<const float4*>(sboxes)[gbase + 192 + lane]; \
        keep_out[dst] = 1.0f; \
    } \
    base += c0 + c1 + c2 + c3; \
    { \
        U64 kk0 = k0, kk1 = k1, kk2 = k2, kk3 = k3; \
        U64 A0=0,A1=0,A2=0,A3=0,A4=0, B0=0,B1=0,B2=0,B3=0,B4=0; \
        U64 C0=0,C1=0,C2=0,C3=0,C4=0, D0=0,D1=0,D2=0,D3=0,D4=0; \
        const int wmin = g_ * 4 + 4; \
        const bool gw0 = (lane >= wmin); \
        const bool gw1 = (64 + lane >= wmin); \
        const bool gw2 = (128 + lane >= wmin); \
        const bool gw3 = (192 + lane >= wmin); \
        const bool gw4 = (256 + lane >= wmin) && (256 + lane < NW); \
        while (kk0 | kk1 | kk2 | kk3) { \
            POPR(ra0); POPR(ra1); POPR(ra2); POPR(ra3); \
            POPR(rb0); POPR(rb1); POPR(rb2); POPR(rb3); \
            POPR(rc0); POPR(rc1); POPR(rc2); POPR(rc3); \
            POPR(rd0); POPR(rd1); POPR(rd2); POPR(rd3); \
            if (ra1 < 0) ra1 = ra0; if (ra2 < 0) ra2 = ra0; if (ra3 < 0) ra3 = ra0; \
            if (rb0 < 0) rb0 = ra0; if (rb1 < 0) rb1 = ra0; if (rb2 < 0) rb2 = ra0; if (rb3 < 0) rb3 = ra0; \
            if (rc0 < 0) rc0 = ra0; if (rc1 < 0) rc1 = ra0; if (rc2 < 0) rc2 = ra0; if (rc3 < 0) rc3 = ra0; \
            if (rd0 < 0) rd0 = ra0; if (rd1 < 0) rd1 = ra0; if (rd2 < 0) rd2 = ra0; if (rd3 < 0) rd3 = ra0; \
            const U64* qa0 = mask + (size_t)(gbase + ra0) * MSTRIDE; \
            const U64* qa1 = mask + (size_t)(gbase + ra1) * MSTRIDE; \
            const U64* qa2 = mask + (size_t)(gbase + ra2) * MSTRIDE; \
            const U64* qa3 = mask + (size_t)(gbase + ra3) * MSTRIDE; \
            const U64* qb0 = mask + (size_t)(gbase + rb0) * MSTRIDE; \
            const U64* qb1 = mask + (size_t)(gbase + rb1) * MSTRIDE; \
            const U64* qb2 = mask + (size_t)(gbase + rb2) * MSTRIDE; \
            const U64* qb3 = mask + (size_t)(gbase + rb3) * MSTRIDE; \
            const U64* qc0 = mask + (size_t)(gbase + rc0) * MSTRIDE; \
            const U64* qc1 = mask + (size_t)(gbase + rc1) * MSTRIDE; \
            const U64* qc2 = mask + (size_t)(gbase + rc2) * MSTRIDE; \
            const U64* qc3 = mask + (size_t)(gbase + rc3) * MSTRIDE; \
            const U64* qd0 = mask + (size_t)(gbase + rd0) * MSTRIDE; \
            const U64* qd1 = mask + (size_t)(gbase + rd1) * MSTRIDE; \
            const U64* qd2 = mask + (size_t)(gbase + rd2) * MSTRIDE; \
            const U64* qd3 = mask + (size_t)(gbase + rd3) * MSTRIDE; \
            if (gw0) { \
                A0 |= qa0[lane] | qa1[lane] | qa2[lane] | qa3[lane]; \
                B0 |= qb0[lane] | qb1[lane] | qb2[lane] | qb3[lane]; \
                C0 |= qc0[lane] | qc1[lane] | qc2[lane] | qc3[lane]; \
                D0 |= qd0[lane] | qd1[lane] | qd2[lane] | qd3[lane]; \
            } \
            if (gw1) { \
                A1 |= qa0[64 + lane] | qa1[64 + lane] | qa2[64 + lane] | qa3[64 + lane]; \
                B1 |= qb0[64 + lane] | qb1[64 + lane] | qb2[64 + lane] | qb3[64 + lane]; \
                C1 |= qc0[64 + lane] | qc1[64 + lane] | qc2[64 + lane] | qc3[64 + lane]; \
                D1 |= qd0[64 + lane] | qd1[64 + lane] | qd2[64 + lane] | qd3[64 + lane]; \
            } \
            if (gw2) { \
                A2 |= qa0[128 + lane] | qa1[128 + lane] | qa2[128 + lane] | qa3[128 + lane]; \
                B2 |= qb0[128 + lane] | qb1[128 + lane] | qb2[128 + lane] | qb3[128 + lane]; \
                C2 |= qc0[128 + lane] | qc1[128 + lane] | qc2[128 + lane] | qc3[128 + lane]; \
                D2 |= qd0[128 + lane] | qd1[128 + lane] | qd2[128 + lane] | qd3[128 + lane]; \
            } \
            if (gw3) { \
                A3 |= qa0[192 + lane] | qa1[192 + lane] | qa2[192 + lane] | qa3[192 + lane]; \
                B3 |= qb0[192 + lane] | qb1[192 + lane] | qb2[192 + lane] | qb3[192 + lane]; \
                C3 |= qc0[192 + lane] | qc1[192 + lane] | qc2[192 + lane] | qc3[192 + lane]; \
                D3 |= qd0[192 + lane] | qd1[192 + lane] | qd2[192 + lane] | qd3[192 + lane]; \
            } \
            if (gw4) { \
                A4 |= qa0[256 + lane] | qa1[256 + lane] | qa2[256 + lane] | qa3[256 + lane]; \
                B4 |= qb0[256 + lane] | qb1[256 + lane] | qb2[256 + lane] | qb3[256 + lane]; \
                C4 |= qc0[256 + lane] | qc1[256 + lane] | qc2[256 + lane] | qc3[256 + lane]; \
                D4 |= qd0[256 + lane] | qd1[256 + lane] | qd2[256 + lane] | qd3[256 + lane]; \
            } \
        } \
        m0 |= A0 | B0 | C0 | D0; \
        m1 |= A1 | B1 | C1 | D1; \
        m2 |= A2 | B2 | C2 | D2; \
        m3 |= A3 | B3 | C3 | D3; \
        m4 |= A4 | B4 | C4 | D4; \
    } \
} while (0)

__global__ __launch_bounds__(64) void k_sweep(const U64* __restrict__ mask,
                                              const U64* __restrict__ diagX,
                                              const float* __restrict__ sboxes,
                                              float* __restrict__ rois_out,
                                              float* __restrict__ keep_out) {
    int lane = threadIdx.x;
    U64 m0 = 0, m1 = 0, m2 = 0, m3 = 0, m4 = 0;
    unsigned base = 0;
    DVARS(dA);
    DVARS(dB);
    LOADD(dA, 0);
    for (int g = 0; g < NG; g += 2) {
        STEP(g, dA, dB);
        if (g + 1 < NG) STEP(g + 1, dB, dA);
    }
}

// ---------------- launch ----------------
extern "C" void kernel_launch(void* const* d_in, const int* in_sizes, int n_in,
                              void* d_out, int out_size, void* d_ws, size_t ws_size,
                              hipStream_t stream) {
    const float* fm      = (const float*)d_in[0];
    const float* conv_w  = (const float*)d_in[2];
    const float* conv_b  = (const float*)d_in[3];
    const float* score_w = (const float*)d_in[4];
    const float* score_b = (const float*)d_in[5];
    const float* loc_w   = (const float*)d_in[6];
    const float* loc_b   = (const float*)d_in[7];

    float* out = (float*)d_out;
    float* rois_out  = out;
    float* keep_out  = out + NBOX * 4;
    float* anch_out  = out + NBOX * 5;
    float* loc_out   = out + NBOX * 9;
    float* score_out = out + NBOX * 13;

    if (ws_size < WS_NEED) {
        k_sentinel<<<(out_size + 255) / 256, 256, 0, stream>>>(out, out_size);
        return;
    }

    char* ws = (char*)d_ws;
    float* in_tT   = (float*)(ws + OFF_INT);
    float* w2      = (float*)(ws + OFF_WT);
    float* partial = (float*)(ws + OFF_PART);
    U64*   mask    = (U64*)(ws + OFF_MASK);
    U64*   diagX   = (U64*)(ws + OFF_DIAG);
    float* mid     = (float*)(ws + OFF_MID);
    float* fg      = (float*)(ws + OFF_FG);
    float* boxes   = (float*)(ws + OFF_BOX);
    float* sboxes  = (float*)(ws + OFF_SBOX);
    float* sarea   = (float*)(ws + OFF_SAREA);
    int*   cntb    = (int*)(ws + OFF_CNT);

    hipMemsetAsync(in_tT, 0, SZ_INT, stream);
    k_in_t<<<(CIN * H * W + 255) / 256, 256, 0, stream>>>(fm, in_tT);
    k_w_t<<<(CMID * CIN * 9 + 255) / 256, 256, 0, stream>>>(conv_w, w2);
    k_conv<<<504, 256, 0, stream>>>(in_tT, w2, partial);
    k_reduce<<<P, 256, 0, stream>>>(partial, conv_b, mid);
    k_heads<<<(P + 15) / 16, 256, 0, stream>>>(mid, score_w, score_b, loc_w, loc_b,
                                               score_out, loc_out, anch_out, fg, boxes);
    hipMemsetAsync(cntb, 0, NBOX * 4, stream);
    k_rank_part<<<dim3((NBOX + 255) / 256, 8), 256, 0, stream>>>(fg, cntb);
    k_scatter<<<(NBOX + 255) / 256, 256, 0, stream>>>(cntb, boxes, sboxes, sarea);
    hipMemsetAsync(rois_out, 0, (size_t)NBOX * 5 * 4, stream);  // rois_out + keep
    hipMemsetAsync(diagX, 0, SZ_DIAG, stream);
    k_maskfill<<<dim3((NBOX + 255) / 256, NW), 256, 0, stream>>>(sboxes, sarea, mask, diagX);
    k_sweep<<<1, 64, 0, stream>>>(mask, diagX, sboxes, rois_out, keep_out);
}

// Round 11
// 936.383 us; speedup vs baseline: 1.0633x; 1.0016x over previous
//
#include <hip/hip_runtime.h>
#include <cstdint>

#define U64 unsigned long long

static constexpr int H = 38, W = 50, P = 1900;        // feature map
static constexpr int CIN = 2048, CMID = 256;
static constexpr int NA = 9, NBOX = 17100;            // 1900*9
static constexpr int HP = 40, WP = 52, QP = HP * WP;  // padded positions (2080)
static constexpr int TPITCH = 2084;                   // in_tT row pitch (floats), mult of 4
static constexpr int KS = 7;                          // split-K over cin
static constexpr int NW = 268;                        // u64 words covering NBOX bits
static constexpr int MSTRIDE = 272;                   // mask row stride (words)
static constexpr int NG = 67;                         // 256-box groups
static constexpr float NMS_T = 0.5f;
static constexpr int QTILE = 256;

// ---------------- ws layout (bytes) ----------------
static constexpr size_t SZ_INT  = (size_t)CIN * TPITCH * 4;   // 17,072,128
static constexpr size_t SZ_WT   = (size_t)9 * CIN * CMID * 4; // 18,874,368
static constexpr size_t SZ_PART = (size_t)KS * P * CMID * 4;  // 13,619,200
static constexpr size_t OFF_INT  = 0;
static constexpr size_t OFF_WT   = OFF_INT + SZ_INT;
static constexpr size_t OFF_PART = OFF_WT + SZ_WT;
static constexpr size_t REGA     = OFF_PART + SZ_PART;        // 49,565,696
// region A overlay (dead after k_reduce): mask + diag 256-blocks
static constexpr size_t OFF_MASK = 0;                          // mask [NBOX][MSTRIDE] (37.2 MB)
static constexpr size_t SZ_MASK  = (size_t)NBOX * MSTRIDE * 8; // 37,209,600
static constexpr size_t OFF_DIAG = SZ_MASK;                    // diagX [67][4][4][64] u64 (549 KB)
static constexpr size_t SZ_DIAG  = (size_t)NG * 1024 * 8;      // 548,864
static constexpr size_t OFF_MID  = REGA;
static constexpr size_t OFF_FG   = OFF_MID + 1945600;
static constexpr size_t OFF_BOX  = OFF_FG + 68608;
static constexpr size_t OFF_SBOX = OFF_BOX + 273664;
static constexpr size_t OFF_SAREA= OFF_SBOX + 273664;
static constexpr size_t OFF_CNT  = OFF_SAREA + 68608;
static constexpr size_t WS_NEED  = OFF_CNT + 68608;            // ~52.26 MB (unchanged)

__device__ __forceinline__ U64 rdlane64(U64 v, int l) {
    unsigned lo = (unsigned)__builtin_amdgcn_readlane((int)(unsigned)(v & 0xffffffffull), l);
    unsigned hi = (unsigned)__builtin_amdgcn_readlane((int)(unsigned)(v >> 32), l);
    return ((U64)hi << 32) | (U64)lo;
}

__device__ __forceinline__ U64 vmaskw(int wg) {
    int rem = NBOX - wg * 64;
    if (rem >= 64) return ~0ull;
    if (rem <= 0) return 0ull;
    return (1ull << rem) - 1ull;
}

// ---------------- kernels ----------------

__global__ __launch_bounds__(256) void k_sentinel(float* out, int n) {
    int i = blockIdx.x * 256 + threadIdx.x;
    if (i < n) out[i] = 1.2345678e8f;
}

// feature_map [CIN][H][W] -> in_tT [CIN][TPITCH] (padded image rows; memset first)
__global__ __launch_bounds__(256) void k_in_t(const float* __restrict__ fm, float* __restrict__ in_tT) {
    int idx = blockIdx.x * 256 + threadIdx.x;
    if (idx >= CIN * (H * W)) return;
    int ci = idx / (H * W), hw = idx - ci * (H * W);
    int h = hw / W, w = hw - h * W;
    in_tT[(size_t)ci * TPITCH + (h + 1) * WP + 1 + w] = fm[idx];
}

// conv_w [CMID][CIN][3][3] -> w2 [y(8)][sub(4)][ci(2048)][k(9)][c(8)]
__global__ __launch_bounds__(256) void k_w_t(const float* __restrict__ cw, float* __restrict__ w2) {
    int idx = blockIdx.x * 256 + threadIdx.x;
    if (idx >= CMID * CIN * 9) return;
    int co = idx / (CIN * 9);
    int rem = idx - co * (CIN * 9);
    int ci = rem / 9, k = rem - ci * 9;
    w2[((size_t)(co >> 3) * CIN + ci) * 72 + k * 8 + (co & 7)] = cw[idx];
}

// 3x3 conv, split-K. grid 504 = 9 qtiles x 8 cout-groups x 7 z (XCD-swizzled).
__global__ __launch_bounds__(256, 2) void k_conv(const float* __restrict__ in_tT,
                                                 const float* __restrict__ w2,
                                                 float* __restrict__ partial) {
    __shared__ float4 s_in4[16 * 104];   // 16 ci x 104 skewed quads (26.6 KB)
    int t = threadIdx.x;
    int lane = t & 63;
    int sub = __builtin_amdgcn_readfirstlane(t >> 6);   // wave-uniform SGPR

    int raw = blockIdx.x;
    int xcd = raw & 7, i0 = raw >> 3;
    int L = xcd * 63 + i0;          // 504 = 8*63, bijective
    int z = L / 72;
    int r0 = L - z * 72;
    int bx = r0 % 9, by = r0 / 9;
    int q0 = bx * QTILE;
    int cout0 = by * 32;
    int cin0 = (z <= 1) ? 304 * z : 608 + 288 * (z - 2);   // 304,304,288x5
    int cin1 = cin0 + ((z <= 1) ? 304 : 288);

    float acc[4][8];
#pragma unroll
    for (int j = 0; j < 4; ++j)
#pragma unroll
        for (int c = 0; c < 8; ++c) acc[j][c] = 0.f;

    const float* wbase = w2 + (size_t)(by * 4 + sub) * CIN * 72;

    for (int c0 = cin0; c0 < cin1; c0 += 16) {
        for (int idx = t; idx < 16 * 92; idx += 256) {
            int r = idx / 92, j = idx - r * 92;
            int qf = q0 - 56 + 4 * j;
            float4 v = make_float4(0.f, 0.f, 0.f, 0.f);
            if (qf >= 0 && qf <= 2080)
                v = *reinterpret_cast<const float4*>(in_tT + (size_t)(c0 + r) * TPITCH + qf);
            s_in4[r * 104 + j + (j >> 3)] = v;
        }
        __syncthreads();
#pragma unroll 1
        for (int r = 0; r < 16; ++r) {
            const float4* row4 = s_in4 + r * 104;
            const float4* w4 = reinterpret_cast<const float4*>(wbase + (size_t)(c0 + r) * 72);
#pragma unroll
            for (int dy = 0; dy < 3; ++dy) {
                int v0 = lane + 13 * dy;
                int v1 = v0 + 1, v2 = v0 + 2;
                float4 F0 = row4[v0 + (v0 >> 3)];
                float4 F1 = row4[v1 + (v1 >> 3)];
                float4 F2 = row4[v2 + (v2 >> 3)];
                float F[12] = {F0.x, F0.y, F0.z, F0.w, F1.x, F1.y, F1.z, F1.w,
                               F2.x, F2.y, F2.z, F2.w};
#pragma unroll
                for (int dxi = 0; dxi < 3; ++dxi) {
                    int k = dy * 3 + dxi;
                    float4 wa = w4[k * 2], wb = w4[k * 2 + 1];
                    float wv[8] = {wa.x, wa.y, wa.z, wa.w, wb.x, wb.y, wb.z, wb.w};
#pragma unroll
                    for (int jj = 0; jj < 4; ++jj) {
                        float iv = F[jj + dxi + 3];
#pragma unroll
                        for (int c = 0; c < 8; ++c) acc[jj][c] += iv * wv[c];
                    }
                }
            }
        }
        __syncthreads();
    }
    float* part = partial + (size_t)z * P * CMID;
#pragma unroll
    for (int jj = 0; jj < 4; ++jj) {
        int q = q0 + 4 * lane + jj;
        if (q < QP) {
            int hp = q / WP, wp_ = q - hp * WP;
            if (hp >= 1 && hp <= H && wp_ >= 1 && wp_ <= W) {
                int p = (hp - 1) * W + (wp_ - 1);
                float* dst = part + (size_t)p * CMID + cout0 + sub * 8;
                float4* d4 = reinterpret_cast<float4*>(dst);
                d4[0] = make_float4(acc[jj][0], acc[jj][1], acc[jj][2], acc[jj][3]);
                d4[1] = make_float4(acc[jj][4], acc[jj][5], acc[jj][6], acc[jj][7]);
            }
        }
    }
}

// sum partials + bias + relu -> mid [P][CMID]
__global__ __launch_bounds__(256) void k_reduce(const float* __restrict__ partial,
                                                const float* __restrict__ bias,
                                                float* __restrict__ mid) {
    int p = blockIdx.x, c = threadIdx.x;
    float s = bias[c];
    for (int ks = 0; ks < KS; ++ks) s += partial[(size_t)ks * P * CMID + (size_t)p * CMID + c];
    mid[(size_t)p * CMID + c] = fmaxf(s, 0.f);
}

// 1x1 heads + softmax + anchors + loc2bbox + clip. 16 positions per block (4 reps).
__global__ __launch_bounds__(256) void k_heads(const float* __restrict__ mid,
                                               const float* __restrict__ score_w,
                                               const float* __restrict__ score_b,
                                               const float* __restrict__ loc_w,
                                               const float* __restrict__ loc_b,
                                               float* __restrict__ score_out,
                                               float* __restrict__ loc_out,
                                               float* __restrict__ anch_out,
                                               float* __restrict__ fg,
                                               float* __restrict__ boxes) {
    __shared__ float wl[256][56];
    __shared__ float bias[56];
    __shared__ float dots[4][64];
    int t = threadIdx.x;
    for (int idx = t; idx < 18 * 256; idx += 256) {
        int c = idx >> 8, i = idx & 255;
        wl[i][c] = score_w[idx];
    }
    for (int idx = t; idx < 36 * 256; idx += 256) {
        int c = idx >> 8, i = idx & 255;
        wl[i][18 + c] = loc_w[idx];
    }
    if (t < 18) bias[t] = score_b[t];
    else if (t < 54) bias[t] = loc_b[t - 18];
    __syncthreads();

    int pl = t >> 6, c = t & 63;
    for (int rep = 0; rep < 4; ++rep) {
        int p = blockIdx.x * 16 + rep * 4 + pl;
        if (c < 54 && p < P) {
            float d = bias[c];
            const float4* mp = reinterpret_cast<const float4*>(mid + (size_t)p * CMID);
            for (int i4 = 0; i4 < 64; ++i4) {
                float4 m4 = mp[i4];
                int i = i4 * 4;
                d += m4.x * wl[i][c] + m4.y * wl[i + 1][c] + m4.z * wl[i + 2][c] + m4.w * wl[i + 3][c];
            }
            dots[pl][c] = d;
        }
        __syncthreads();
        if (c < NA && p < P) {
            int a = c;
            int idx = p * NA + a;
            float l0 = dots[pl][2 * a], l1 = dots[pl][2 * a + 1];
            float mx = fmaxf(l0, l1);
            float e0 = expf(l0 - mx), e1 = expf(l1 - mx);
            float den = e0 + e1;
            float s0 = e0 / den, s1 = e1 / den;
            score_out[(size_t)idx * 2 + 0] = s0;
            score_out[(size_t)idx * 2 + 1] = s1;
            fg[idx] = s1;
            float dx = dots[pl][18 + 4 * a + 0];
            float dy = dots[pl][18 + 4 * a + 1];
            float dw = dots[pl][18 + 4 * a + 2];
            float dh = dots[pl][18 + 4 * a + 3];
            loc_out[(size_t)idx * 4 + 0] = dx;
            loc_out[(size_t)idx * 4 + 1] = dy;
            loc_out[(size_t)idx * 4 + 2] = dw;
            loc_out[(size_t)idx * 4 + 3] = dh;
            int hh = p / W, ww = p % W;
            const double scales[3] = {8.0, 16.0, 32.0};
            const double ratios[3] = {0.5, 1.0, 2.0};
            double s = scales[a / 3], r = ratios[a % 3];
            double wb2 = 16.0 * s * sqrt(r);
            double hb = wb2 / r;
            double xmin = 8.0 - wb2 / 2.0, ymin = 8.0 - hb / 2.0;
            float b0 = (float)xmin, b1 = (float)ymin;
            float b2 = (float)(xmin + wb2), b3 = (float)(ymin + hb);
            float gx = (float)(ww * 16), gy = (float)(hh * 16);
            float a0 = gx + b0, a1 = gy + b1, a2 = gx + b2, a3 = gy + b3;
            anch_out[(size_t)idx * 4 + 0] = a0;
            anch_out[(size_t)idx * 4 + 1] = a1;
            anch_out[(size_t)idx * 4 + 2] = a2;
            anch_out[(size_t)idx * 4 + 3] = a3;
            float aw = a2 - a0, ah = a3 - a1;
            float cx = a0 + 0.5f * aw, cy = a1 + 0.5f * ah;
            float ncx = dx * aw + cx, ncy = dy * ah + cy;
            float nw = expf(dw) * aw, nh = expf(dh) * ah;
            float x1 = ncx - 0.5f * nw, y1 = ncy - 0.5f * nh;
            float x2 = ncx + 0.5f * nw, y2 = ncy + 0.5f * nh;
            x1 = fminf(fmaxf(x1, 0.f), (float)(W * 16));
            x2 = fminf(fmaxf(x2, 0.f), (float)(W * 16));
            y1 = fminf(fmaxf(y1, 0.f), (float)(H * 16));
            y2 = fminf(fmaxf(y2, 0.f), (float)(H * 16));
            float4* bp = reinterpret_cast<float4*>(boxes);
            bp[idx] = make_float4(x1, y1, x2, y2);
        }
        __syncthreads();
    }
}

// partial stable-descending rank counts over a j-slice. grid (67, 8)
static constexpr int JSL = 2144;  // slice size (mult of 4)
__global__ __launch_bounds__(256) void k_rank_part(const float* __restrict__ fg,
                                                   int* __restrict__ cntb) {
    __shared__ float4 tile[256];
    int t = threadIdx.x;
    int i = blockIdx.x * 256 + t;
    int j0 = blockIdx.y * JSL;
    int j1 = min(NBOX, j0 + JSL);
    float my = (i < NBOX) ? fg[i] : 0.f;
    int cnt = 0;
    for (int base = j0; base < j1; base += 1024) {
        int j = base + t * 4;
        float4 v = make_float4(-3.4e38f, -3.4e38f, -3.4e38f, -3.4e38f);
        if (j + 3 < j1) {
            v = *reinterpret_cast<const float4*>(fg + j);
        } else {
            if (j < j1) v.x = fg[j];
            if (j + 1 < j1) v.y = fg[j + 1];
            if (j + 2 < j1) v.z = fg[j + 2];
            if (j + 3 < j1) v.w = fg[j + 3];
        }
        __syncthreads();
        tile[t] = v;
        __syncthreads();
        if (i < NBOX) {
            for (int u = 0; u < 256; ++u) {
                float4 s = tile[u];
                int jb = base + u * 4;
                cnt += (s.x > my) || (s.x == my && jb < i);
                cnt += (s.y > my) || (s.y == my && jb + 1 < i);
                cnt += (s.z > my) || (s.z == my && jb + 2 < i);
                cnt += (s.w > my) || (s.w == my && jb + 3 < i);
            }
        }
    }
    if (i < NBOX && cnt) atomicAdd(&cntb[i], cnt);
}

// scatter boxes to sorted order using rank counts
__global__ __launch_bounds__(256) void k_scatter(const int* __restrict__ cntb,
                                                 const float* __restrict__ boxes,
                                                 float* __restrict__ sboxes,
                                                 float* __restrict__ sarea) {
    int i = blockIdx.x * 256 + threadIdx.x;
    if (i >= NBOX) return;
    int c = cntb[i];
    float4 b = reinterpret_cast<const float4*>(boxes)[i];
    reinterpret_cast<float4*>(sboxes)[c] = b;
    sarea[c] = (b.z - b.x) * (b.w - b.y);
}

// NMS pair bitmask, row-major + diag 256-block bands (diagX memset 0 first).
__global__ __launch_bounds__(256) void k_maskfill(const float* __restrict__ sboxes,
                                                  const float* __restrict__ sarea,
                                                  U64* __restrict__ mask,
                                                  U64* __restrict__ diagX) {
    int w = blockIdx.y;
    int i0 = blockIdx.x * 256;
    if (w < (i0 >> 6)) return;
    __shared__ float4 sb[64];
    __shared__ float sa[64];
    int t = threadIdx.x;
    if (t < 64) {
        int j = w * 64 + t;
        if (j < NBOX) {
            sb[t] = reinterpret_cast<const float4*>(sboxes)[j];
            sa[t] = sarea[j];
        } else {
            sb[t] = make_float4(0.f, 0.f, 0.f, 0.f);
            sa[t] = 0.f;
        }
    }
    __syncthreads();
    int i = i0 + t;
    if (i >= NBOX || w < (i >> 6)) return;
    float4 bi = reinterpret_cast<const float4*>(sboxes)[i];
    float ai = sarea[i];
    U64 word = 0;
#pragma unroll 4
    for (int jb = 0; jb < 64; ++jb) {
        int j = w * 64 + jb;
        float4 bj = sb[jb];
        float xx1 = fmaxf(bi.x, bj.x), yy1 = fmaxf(bi.y, bj.y);
        float xx2 = fminf(bi.z, bj.z), yy2 = fminf(bi.w, bj.w);
        float inter = fmaxf(xx2 - xx1, 0.f) * fmaxf(yy2 - yy1, 0.f);
        float iou = inter / (ai + sa[jb] - inter);
        word |= ((U64)((iou > NMS_T) && (j > i))) << jb;
    }
    mask[(size_t)i * MSTRIDE + w] = word;
    int gi = i >> 8;
    int wl = w - gi * 4;
    if (wl >= 0 && wl < 4)
        diagX[(size_t)gi * 1024 + wl * 256 + (i & 255)] = word;
}

// ---- sweep v8 == v7 logic + __launch_bounds__(64,1) so the 170+ VGPRs of
//      live state actually stay in registers (v7 spilled: VGPR_Count=60).
#define DVARS(P) U64 P##00, P##01, P##02, P##03, P##10, P##11, P##12, P##13, \
                     P##20, P##21, P##22, P##23, P##30, P##31, P##32, P##33

#define LOADD(P, G) do { \
    const U64* _dp = diagX + (size_t)(G) * 1024 + lane; \
    P##00 = _dp[0];   P##01 = _dp[64];  P##02 = _dp[128]; P##03 = _dp[192]; \
    P##10 = _dp[256]; P##11 = _dp[320]; P##12 = _dp[384]; P##13 = _dp[448]; \
    P##20 = _dp[512]; P##21 = _dp[576]; P##22 = _dp[640]; P##23 = _dp[704]; \
    P##30 = _dp[768]; P##31 = _dp[832]; P##32 = _dp[896]; P##33 = _dp[960]; \
} while (0)

#define ZEROD(P) do { \
    P##00 = P##01 = P##02 = P##03 = P##10 = P##11 = P##12 = P##13 = 0; \
    P##20 = P##21 = P##22 = P##23 = P##30 = P##31 = P##32 = P##33 = 0; \
} while (0)

#define POPR(R) \
    int R; \
    do { \
        if (kk0) { int _i = (int)__builtin_ctzll(kk0); kk0 &= kk0 - 1; R = _i; } \
        else if (kk1) { int _i = (int)__builtin_ctzll(kk1); kk1 &= kk1 - 1; R = 64 + _i; } \
        else if (kk2) { int _i = (int)__builtin_ctzll(kk2); kk2 &= kk2 - 1; R = 128 + _i; } \
        else if (kk3) { int _i = (int)__builtin_ctzll(kk3); kk3 &= kk3 - 1; R = 192 + _i; } \
        else R = -1; \
    } while (0)

#define STEP(G, DU, DN) do { \
    const int g_ = (G); \
    if (g_ + 1 < NG) { LOADD(DN, g_ + 1); } else { ZEROD(DN); } \
    const int gbase = g_ * 256; \
    int rsel = g_ >> 4; \
    U64 msel = (rsel == 0) ? m0 : (rsel == 1) ? m1 : (rsel == 2) ? m2 : (rsel == 3) ? m3 : m4; \
    int lb = (g_ * 4) & 63; \
    U64 mc0 = rdlane64(msel, lb), mc1 = rdlane64(msel, lb + 1); \
    U64 mc2 = rdlane64(msel, lb + 2), mc3 = rdlane64(msel, lb + 3); \
    U64 ns0 = ~mc0 & vmaskw(g_ * 4),     ns1 = ~mc1 & vmaskw(g_ * 4 + 1); \
    U64 ns2 = ~mc2 & vmaskw(g_ * 4 + 2), ns3 = ~mc3 & vmaskw(g_ * 4 + 3); \
    U64 k0 = 0, k1 = 0, k2 = 0, k3 = 0; \
    while (ns0) { \
        int i = (int)__builtin_ctzll(ns0); \
        k0 |= 1ull << i; \
        ns0 &= ~(rdlane64(DU##00, i) | (1ull << i)); \
        ns1 &= ~rdlane64(DU##10, i); \
        ns2 &= ~rdlane64(DU##20, i); \
        ns3 &= ~rdlane64(DU##30, i); \
    } \
    while (ns1) { \
        int i = (int)__builtin_ctzll(ns1); \
        k1 |= 1ull << i; \
        ns1 &= ~(rdlane64(DU##11, i) | (1ull << i)); \
        ns2 &= ~rdlane64(DU##21, i); \
        ns3 &= ~rdlane64(DU##31, i); \
    } \
    while (ns2) { \
        int i = (int)__builtin_ctzll(ns2); \
        k2 |= 1ull << i; \
        ns2 &= ~(rdlane64(DU##22, i) | (1ull << i)); \
        ns3 &= ~rdlane64(DU##32, i); \
    } \
    while (ns3) { \
        int i = (int)__builtin_ctzll(ns3); \
        k3 |= 1ull << i; \
        ns3 &= ~(rdlane64(DU##33, i) | (1ull << i)); \
    } \
    unsigned c0 = (unsigned)__popcll(k0), c1 = (unsigned)__popcll(k1); \
    unsigned c2 = (unsigned)__popcll(k2), c3 = (unsigned)__popcll(k3); \
    U64 lmask = (1ull << lane) - 1ull; \
    if ((k0 >> lane) & 1) { \
        unsigned dst = base + (unsigned)__popcll(k0 & lmask); \
        reinterpret_cast<float4*>(rois_out)[dst] = reinterpret_cast<const float4*>(sboxes)[gbase + lane]; \
        keep_out[dst] = 1.0f; \
    } \
    if ((k1 >> lane) & 1) { \
        unsigned dst = base + c0 + (unsigned)__popcll(k1 & lmask); \
        reinterpret_cast<float4*>(rois_out)[dst] = reinterpret_cast<const float4*>(sboxes)[gbase + 64 + lane]; \
        keep_out[dst] = 1.0f; \
    } \
    if ((k2 >> lane) & 1) { \
        unsigned dst = base + c0 + c1 + (unsigned)__popcll(k2 & lmask); \
        reinterpret_cast<float4*>(rois_out)[dst] = reinterpret_cast<const float4*>(sboxes)[gbase + 128 + lane]; \
        keep_out[dst] = 1.0f; \
    } \
    if ((k3 >> lane) & 1) { \
        unsigned dst = base + c0 + c1 + c2 + (unsigned)__popcll(k3 & lmask); \
        reinterpret_cast<float4*>(rois_out)[dst] = reinterpret_cast<const float4*>(sboxes)[gbase + 192 + lane]; \
        keep_out[dst] = 1.0f; \
    } \
    base += c0 + c1 + c2 + c3; \
    { \
        U64 kk0 = k0, kk1 = k1, kk2 = k2, kk3 = k3; \
        U64 A0=0,A1=0,A2=0,A3=0,A4=0, B0=0,B1=0,B2=0,B3=0,B4=0; \
        U64 C0=0,C1=0,C2=0,C3=0,C4=0, D0=0,D1=0,D2=0,D3=0,D4=0; \
        const int wmin = g_ * 4 + 4; \
        const bool gw0 = (lane >= wmin); \
        const bool gw1 = (64 + lane >= wmin); \
        const bool gw2 = (128 + lane >= wmin); \
        const bool gw3 = (192 + lane >= wmin); \
        const bool gw4 = (256 + lane >= wmin) && (256 + lane < NW); \
        while (kk0 | kk1 | kk2 | kk3) { \
            POPR(ra0); POPR(ra1); POPR(ra2); POPR(ra3); \
            POPR(rb0); POPR(rb1); POPR(rb2); POPR(rb3); \
            POPR(rc0); POPR(rc1); POPR(rc2); POPR(rc3); \
            POPR(rd0); POPR(rd1); POPR(rd2); POPR(rd3); \
            if (ra1 < 0) ra1 = ra0; if (ra2 < 0) ra2 = ra0; if (ra3 < 0) ra3 = ra0; \
            if (rb0 < 0) rb0 = ra0; if (rb1 < 0) rb1 = ra0; if (rb2 < 0) rb2 = ra0; if (rb3 < 0) rb3 = ra0; \
            if (rc0 < 0) rc0 = ra0; if (rc1 < 0) rc1 = ra0; if (rc2 < 0) rc2 = ra0; if (rc3 < 0) rc3 = ra0; \
            if (rd0 < 0) rd0 = ra0; if (rd1 < 0) rd1 = ra0; if (rd2 < 0) rd2 = ra0; if (rd3 < 0) rd3 = ra0; \
            const U64* qa0 = mask + (size_t)(gbase + ra0) * MSTRIDE; \
            const U64* qa1 = mask + (size_t)(gbase + ra1) * MSTRIDE; \
            const U64* qa2 = mask + (size_t)(gbase + ra2) * MSTRIDE; \
            const U64* qa3 = mask + (size_t)(gbase + ra3) * MSTRIDE; \
            const U64* qb0 = mask + (size_t)(gbase + rb0) * MSTRIDE; \
            const U64* qb1 = mask + (size_t)(gbase + rb1) * MSTRIDE; \
            const U64* qb2 = mask + (size_t)(gbase + rb2) * MSTRIDE; \
            const U64* qb3 = mask + (size_t)(gbase + rb3) * MSTRIDE; \
            const U64* qc0 = mask + (size_t)(gbase + rc0) * MSTRIDE; \
            const U64* qc1 = mask + (size_t)(gbase + rc1) * MSTRIDE; \
            const U64* qc2 = mask + (size_t)(gbase + rc2) * MSTRIDE; \
            const U64* qc3 = mask + (size_t)(gbase + rc3) * MSTRIDE; \
            const U64* qd0 = mask + (size_t)(gbase + rd0) * MSTRIDE; \
            const U64* qd1 = mask + (size_t)(gbase + rd1) * MSTRIDE; \
            const U64* qd2 = mask + (size_t)(gbase + rd2) * MSTRIDE; \
            const U64* qd3 = mask + (size_t)(gbase + rd3) * MSTRIDE; \
            if (gw0) { \
                A0 |= qa0[lane] | qa1[lane] | qa2[lane] | qa3[lane]; \
                B0 |= qb0[lane] | qb1[lane] | qb2[lane] | qb3[lane]; \
                C0 |= qc0[lane] | qc1[lane] | qc2[lane] | qc3[lane]; \
                D0 |= qd0[lane] | qd1[lane] | qd2[lane] | qd3[lane]; \
            } \
            if (gw1) { \
                A1 |= qa0[64 + lane] | qa1[64 + lane] | qa2[64 + lane] | qa3[64 + lane]; \
                B1 |= qb0[64 + lane] | qb1[64 + lane] | qb2[64 + lane] | qb3[64 + lane]; \
                C1 |= qc0[64 + lane] | qc1[64 + lane] | qc2[64 + lane] | qc3[64 + lane]; \
                D1 |= qd0[64 + lane] | qd1[64 + lane] | qd2[64 + lane] | qd3[64 + lane]; \
            } \
            if (gw2) { \
                A2 |= qa0[128 + lane] | qa1[128 + lane] | qa2[128 + lane] | qa3[128 + lane]; \
                B2 |= qb0[128 + lane] | qb1[128 + lane] | qb2[128 + lane] | qb3[128 + lane]; \
                C2 |= qc0[128 + lane] | qc1[128 + lane] | qc2[128 + lane] | qc3[128 + lane]; \
                D2 |= qd0[128 + lane] | qd1[128 + lane] | qd2[128 + lane] | qd3[128 + lane]; \
            } \
            if (gw3) { \
                A3 |= qa0[192 + lane] | qa1[192 + lane] | qa2[192 + lane] | qa3[192 + lane]; \
                B3 |= qb0[192 + lane] | qb1[192 + lane] | qb2[192 + lane] | qb3[192 + lane]; \
                C3 |= qc0[192 + lane] | qc1[192 + lane] | qc2[192 + lane] | qc3[192 + lane]; \
                D3 |= qd0[192 + lane] | qd1[192 + lane] | qd2[192 + lane] | qd3[192 + lane]; \
            } \
            if (gw4) { \
                A4 |= qa0[256 + lane] | qa1[256 + lane] | qa2[256 + lane] | qa3[256 + lane]; \
                B4 |= qb0[256 + lane] | qb1[256 + lane] | qb2[256 + lane] | qb3[256 + lane]; \
                C4 |= qc0[256 + lane] | qc1[256 + lane] | qc2[256 + lane] | qc3[256 + lane]; \
                D4 |= qd0[256 + lane] | qd1[256 + lane] | qd2[256 + lane] | qd3[256 + lane]; \
            } \
        } \
        m0 |= A0 | B0 | C0 | D0; \
        m1 |= A1 | B1 | C1 | D1; \
        m2 |= A2 | B2 | C2 | D2; \
        m3 |= A3 | B3 | C3 | D3; \
        m4 |= A4 | B4 | C4 | D4; \
    } \
} while (0)

__global__ __launch_bounds__(64, 1) void k_sweep(const U64* __restrict__ mask,
                                                 const U64* __restrict__ diagX,
                                                 const float* __restrict__ sboxes,
                                                 float* __restrict__ rois_out,
                                                 float* __restrict__ keep_out) {
    int lane = threadIdx.x;
    U64 m0 = 0, m1 = 0, m2 = 0, m3 = 0, m4 = 0;
    unsigned base = 0;
    DVARS(dA);
    DVARS(dB);
    LOADD(dA, 0);
    for (int g = 0; g < NG; g += 2) {
        STEP(g, dA, dB);
        if (g + 1 < NG) STEP(g + 1, dB, dA);
    }
}

// ---------------- launch ----------------
extern "C" void kernel_launch(void* const* d_in, const int* in_sizes, int n_in,
                              void* d_out, int out_size, void* d_ws, size_t ws_size,
                              hipStream_t stream) {
    const float* fm      = (const float*)d_in[0];
    const float* conv_w  = (const float*)d_in[2];
    const float* conv_b  = (const float*)d_in[3];
    const float* score_w = (const float*)d_in[4];
    const float* score_b = (const float*)d_in[5];
    const float* loc_w   = (const float*)d_in[6];
    const float* loc_b   = (const float*)d_in[7];

    float* out = (float*)d_out;
    float* rois_out  = out;
    float* keep_out  = out + NBOX * 4;
    float* anch_out  = out + NBOX * 5;
    float* loc_out   = out + NBOX * 9;
    float* score_out = out + NBOX * 13;

    if (ws_size < WS_NEED) {
        k_sentinel<<<(out_size + 255) / 256, 256, 0, stream>>>(out, out_size);
        return;
    }

    char* ws = (char*)d_ws;
    float* in_tT   = (float*)(ws + OFF_INT);
    float* w2      = (float*)(ws + OFF_WT);
    float* partial = (float*)(ws + OFF_PART);
    U64*   mask    = (U64*)(ws + OFF_MASK);
    U64*   diagX   = (U64*)(ws + OFF_DIAG);
    float* mid     = (float*)(ws + OFF_MID);
    float* fg      = (float*)(ws + OFF_FG);
    float* boxes   = (float*)(ws + OFF_BOX);
    float* sboxes  = (float*)(ws + OFF_SBOX);
    float* sarea   = (float*)(ws + OFF_SAREA);
    int*   cntb    = (int*)(ws + OFF_CNT);

    hipMemsetAsync(in_tT, 0, SZ_INT, stream);
    k_in_t<<<(CIN * H * W + 255) / 256, 256, 0, stream>>>(fm, in_tT);
    k_w_t<<<(CMID * CIN * 9 + 255) / 256, 256, 0, stream>>>(conv_w, w2);
    k_conv<<<504, 256, 0, stream>>>(in_tT, w2, partial);
    k_reduce<<<P, 256, 0, stream>>>(partial, conv_b, mid);
    k_heads<<<(P + 15) / 16, 256, 0, stream>>>(mid, score_w, score_b, loc_w, loc_b,
                                               score_out, loc_out, anch_out, fg, boxes);
    hipMemsetAsync(cntb, 0, NBOX * 4, stream);
    k_rank_part<<<dim3((NBOX + 255) / 256, 8), 256, 0, stream>>>(fg, cntb);
    k_scatter<<<(NBOX + 255) / 256, 256, 0, stream>>>(cntb, boxes, sboxes, sarea);
    hipMemsetAsync(rois_out, 0, (size_t)NBOX * 5 * 4, stream);  // rois_out + keep
    hipMemsetAsync(diagX, 0, SZ_DIAG, stream);
    k_maskfill<<<dim3((NBOX + 255) / 256, NW), 256, 0, stream>>>(sboxes, sarea, mask, diagX);
    k_sweep<<<1, 64, 0, stream>>>(mask, diagX, sboxes, rois_out, keep_out);
}

// Round 12
// 764.615 us; speedup vs baseline: 1.3021x; 1.2246x over previous
//
#include <hip/hip_runtime.h>
#include <cstdint>

#define U64 unsigned long long

static constexpr int H = 38, W = 50, P = 1900;        // feature map
static constexpr int CIN = 2048, CMID = 256;
static constexpr int NA = 9, NBOX = 17100;            // 1900*9
static constexpr int HP = 40, WP = 52, QP = HP * WP;  // padded positions (2080)
static constexpr int TPITCH = 2084;                   // in_tT row pitch (floats), mult of 4
static constexpr int KS = 7;                          // split-K over cin
static constexpr int NW = 268;                        // u64 words covering NBOX bits
static constexpr int MSTRIDE = 272;                   // mask row stride (words)
static constexpr int NG = 67;                         // 256-box groups
static constexpr float NMS_T = 0.5f;
static constexpr int QTILE = 256;

// ---------------- ws layout (bytes) ----------------
static constexpr size_t SZ_INT  = (size_t)CIN * TPITCH * 4;   // 17,072,128
static constexpr size_t SZ_WT   = (size_t)9 * CIN * CMID * 4; // 18,874,368
static constexpr size_t SZ_PART = (size_t)KS * P * CMID * 4;  // 13,619,200
static constexpr size_t OFF_INT  = 0;
static constexpr size_t OFF_WT   = OFF_INT + SZ_INT;
static constexpr size_t OFF_PART = OFF_WT + SZ_WT;
static constexpr size_t REGA     = OFF_PART + SZ_PART;        // 49,565,696
// region A overlay (dead after k_reduce): mask + diag 256-blocks
static constexpr size_t OFF_MASK = 0;                          // mask [NBOX][MSTRIDE] (37.2 MB)
static constexpr size_t SZ_MASK  = (size_t)NBOX * MSTRIDE * 8; // 37,209,600
static constexpr size_t OFF_DIAG = SZ_MASK;                    // diagX [67][4][4][64] u64 (549 KB)
static constexpr size_t SZ_DIAG  = (size_t)NG * 1024 * 8;      // 548,864
static constexpr size_t OFF_MID  = REGA;
static constexpr size_t OFF_FG   = OFF_MID + 1945600;
static constexpr size_t OFF_BOX  = OFF_FG + 68608;
static constexpr size_t OFF_SBOX = OFF_BOX + 273664;
static constexpr size_t OFF_SAREA= OFF_SBOX + 273664;
static constexpr size_t OFF_CNT  = OFF_SAREA + 68608;
static constexpr size_t WS_NEED  = OFF_CNT + 68608;            // ~52.26 MB (unchanged)

__device__ __forceinline__ U64 rdlane64(U64 v, int l) {
    unsigned lo = (unsigned)__builtin_amdgcn_readlane((int)(unsigned)(v & 0xffffffffull), l);
    unsigned hi = (unsigned)__builtin_amdgcn_readlane((int)(unsigned)(v >> 32), l);
    return ((U64)hi << 32) | (U64)lo;
}

__device__ __forceinline__ U64 vmaskw(int wg) {
    int rem = NBOX - wg * 64;
    if (rem >= 64) return ~0ull;
    if (rem <= 0) return 0ull;
    return (1ull << rem) - 1ull;
}

// ---------------- kernels ----------------

__global__ __launch_bounds__(256) void k_sentinel(float* out, int n) {
    int i = blockIdx.x * 256 + threadIdx.x;
    if (i < n) out[i] = 1.2345678e8f;
}

// feature_map [CIN][H][W] -> in_tT [CIN][TPITCH] (padded image rows; memset first)
__global__ __launch_bounds__(256) void k_in_t(const float* __restrict__ fm, float* __restrict__ in_tT) {
    int idx = blockIdx.x * 256 + threadIdx.x;
    if (idx >= CIN * (H * W)) return;
    int ci = idx / (H * W), hw = idx - ci * (H * W);
    int h = hw / W, w = hw - h * W;
    in_tT[(size_t)ci * TPITCH + (h + 1) * WP + 1 + w] = fm[idx];
}

// conv_w [CMID][CIN][3][3] -> w2 [y(8)][sub(4)][ci(2048)][k(9)][c(8)]
__global__ __launch_bounds__(256) void k_w_t(const float* __restrict__ cw, float* __restrict__ w2) {
    int idx = blockIdx.x * 256 + threadIdx.x;
    if (idx >= CMID * CIN * 9) return;
    int co = idx / (CIN * 9);
    int rem = idx - co * (CIN * 9);
    int ci = rem / 9, k = rem - ci * 9;
    w2[((size_t)(co >> 3) * CIN + ci) * 72 + k * 8 + (co & 7)] = cw[idx];
}

// 3x3 conv, split-K. grid 504 = 9 qtiles x 8 cout-groups x 7 z (XCD-swizzled).
__global__ __launch_bounds__(256, 2) void k_conv(const float* __restrict__ in_tT,
                                                 const float* __restrict__ w2,
                                                 float* __restrict__ partial) {
    __shared__ float4 s_in4[16 * 104];   // 16 ci x 104 skewed quads (26.6 KB)
    int t = threadIdx.x;
    int lane = t & 63;
    int sub = __builtin_amdgcn_readfirstlane(t >> 6);   // wave-uniform SGPR

    int raw = blockIdx.x;
    int xcd = raw & 7, i0 = raw >> 3;
    int L = xcd * 63 + i0;          // 504 = 8*63, bijective
    int z = L / 72;
    int r0 = L - z * 72;
    int bx = r0 % 9, by = r0 / 9;
    int q0 = bx * QTILE;
    int cout0 = by * 32;
    int cin0 = (z <= 1) ? 304 * z : 608 + 288 * (z - 2);   // 304,304,288x5
    int cin1 = cin0 + ((z <= 1) ? 304 : 288);

    float acc[4][8];
#pragma unroll
    for (int j = 0; j < 4; ++j)
#pragma unroll
        for (int c = 0; c < 8; ++c) acc[j][c] = 0.f;

    const float* wbase = w2 + (size_t)(by * 4 + sub) * CIN * 72;

    for (int c0 = cin0; c0 < cin1; c0 += 16) {
        for (int idx = t; idx < 16 * 92; idx += 256) {
            int r = idx / 92, j = idx - r * 92;
            int qf = q0 - 56 + 4 * j;
            float4 v = make_float4(0.f, 0.f, 0.f, 0.f);
            if (qf >= 0 && qf <= 2080)
                v = *reinterpret_cast<const float4*>(in_tT + (size_t)(c0 + r) * TPITCH + qf);
            s_in4[r * 104 + j + (j >> 3)] = v;
        }
        __syncthreads();
#pragma unroll 1
        for (int r = 0; r < 16; ++r) {
            const float4* row4 = s_in4 + r * 104;
            const float4* w4 = reinterpret_cast<const float4*>(wbase + (size_t)(c0 + r) * 72);
#pragma unroll
            for (int dy = 0; dy < 3; ++dy) {
                int v0 = lane + 13 * dy;
                int v1 = v0 + 1, v2 = v0 + 2;
                float4 F0 = row4[v0 + (v0 >> 3)];
                float4 F1 = row4[v1 + (v1 >> 3)];
                float4 F2 = row4[v2 + (v2 >> 3)];
                float F[12] = {F0.x, F0.y, F0.z, F0.w, F1.x, F1.y, F1.z, F1.w,
                               F2.x, F2.y, F2.z, F2.w};
#pragma unroll
                for (int dxi = 0; dxi < 3; ++dxi) {
                    int k = dy * 3 + dxi;
                    float4 wa = w4[k * 2], wb = w4[k * 2 + 1];
                    float wv[8] = {wa.x, wa.y, wa.z, wa.w, wb.x, wb.y, wb.z, wb.w};
#pragma unroll
                    for (int jj = 0; jj < 4; ++jj) {
                        float iv = F[jj + dxi + 3];
#pragma unroll
                        for (int c = 0; c < 8; ++c) acc[jj][c] += iv * wv[c];
                    }
                }
            }
        }
        __syncthreads();
    }
    float* part = partial + (size_t)z * P * CMID;
#pragma unroll
    for (int jj = 0; jj < 4; ++jj) {
        int q = q0 + 4 * lane + jj;
        if (q < QP) {
            int hp = q / WP, wp_ = q - hp * WP;
            if (hp >= 1 && hp <= H && wp_ >= 1 && wp_ <= W) {
                int p = (hp - 1) * W + (wp_ - 1);
                float* dst = part + (size_t)p * CMID + cout0 + sub * 8;
                float4* d4 = reinterpret_cast<float4*>(dst);
                d4[0] = make_float4(acc[jj][0], acc[jj][1], acc[jj][2], acc[jj][3]);
                d4[1] = make_float4(acc[jj][4], acc[jj][5], acc[jj][6], acc[jj][7]);
            }
        }
    }
}

// sum partials + bias + relu -> mid [P][CMID]
__global__ __launch_bounds__(256) void k_reduce(const float* __restrict__ partial,
                                                const float* __restrict__ bias,
                                                float* __restrict__ mid) {
    int p = blockIdx.x, c = threadIdx.x;
    float s = bias[c];
    for (int ks = 0; ks < KS; ++ks) s += partial[(size_t)ks * P * CMID + (size_t)p * CMID + c];
    mid[(size_t)p * CMID + c] = fmaxf(s, 0.f);
}

// 1x1 heads + softmax + anchors + loc2bbox + clip. 16 positions per block (4 reps).
__global__ __launch_bounds__(256) void k_heads(const float* __restrict__ mid,
                                               const float* __restrict__ score_w,
                                               const float* __restrict__ score_b,
                                               const float* __restrict__ loc_w,
                                               const float* __restrict__ loc_b,
                                               float* __restrict__ score_out,
                                               float* __restrict__ loc_out,
                                               float* __restrict__ anch_out,
                                               float* __restrict__ fg,
                                               float* __restrict__ boxes) {
    __shared__ float wl[256][56];
    __shared__ float bias[56];
    __shared__ float dots[4][64];
    int t = threadIdx.x;
    for (int idx = t; idx < 18 * 256; idx += 256) {
        int c = idx >> 8, i = idx & 255;
        wl[i][c] = score_w[idx];
    }
    for (int idx = t; idx < 36 * 256; idx += 256) {
        int c = idx >> 8, i = idx & 255;
        wl[i][18 + c] = loc_w[idx];
    }
    if (t < 18) bias[t] = score_b[t];
    else if (t < 54) bias[t] = loc_b[t - 18];
    __syncthreads();

    int pl = t >> 6, c = t & 63;
    for (int rep = 0; rep < 4; ++rep) {
        int p = blockIdx.x * 16 + rep * 4 + pl;
        if (c < 54 && p < P) {
            float d = bias[c];
            const float4* mp = reinterpret_cast<const float4*>(mid + (size_t)p * CMID);
            for (int i4 = 0; i4 < 64; ++i4) {
                float4 m4 = mp[i4];
                int i = i4 * 4;
                d += m4.x * wl[i][c] + m4.y * wl[i + 1][c] + m4.z * wl[i + 2][c] + m4.w * wl[i + 3][c];
            }
            dots[pl][c] = d;
        }
        __syncthreads();
        if (c < NA && p < P) {
            int a = c;
            int idx = p * NA + a;
            float l0 = dots[pl][2 * a], l1 = dots[pl][2 * a + 1];
            float mx = fmaxf(l0, l1);
            float e0 = expf(l0 - mx), e1 = expf(l1 - mx);
            float den = e0 + e1;
            float s0 = e0 / den, s1 = e1 / den;
            score_out[(size_t)idx * 2 + 0] = s0;
            score_out[(size_t)idx * 2 + 1] = s1;
            fg[idx] = s1;
            float dx = dots[pl][18 + 4 * a + 0];
            float dy = dots[pl][18 + 4 * a + 1];
            float dw = dots[pl][18 + 4 * a + 2];
            float dh = dots[pl][18 + 4 * a + 3];
            loc_out[(size_t)idx * 4 + 0] = dx;
            loc_out[(size_t)idx * 4 + 1] = dy;
            loc_out[(size_t)idx * 4 + 2] = dw;
            loc_out[(size_t)idx * 4 + 3] = dh;
            int hh = p / W, ww = p % W;
            const double scales[3] = {8.0, 16.0, 32.0};
            const double ratios[3] = {0.5, 1.0, 2.0};
            double s = scales[a / 3], r = ratios[a % 3];
            double wb2 = 16.0 * s * sqrt(r);
            double hb = wb2 / r;
            double xmin = 8.0 - wb2 / 2.0, ymin = 8.0 - hb / 2.0;
            float b0 = (float)xmin, b1 = (float)ymin;
            float b2 = (float)(xmin + wb2), b3 = (float)(ymin + hb);
            float gx = (float)(ww * 16), gy = (float)(hh * 16);
            float a0 = gx + b0, a1 = gy + b1, a2 = gx + b2, a3 = gy + b3;
            anch_out[(size_t)idx * 4 + 0] = a0;
            anch_out[(size_t)idx * 4 + 1] = a1;
            anch_out[(size_t)idx * 4 + 2] = a2;
            anch_out[(size_t)idx * 4 + 3] = a3;
            float aw = a2 - a0, ah = a3 - a1;
            float cx = a0 + 0.5f * aw, cy = a1 + 0.5f * ah;
            float ncx = dx * aw + cx, ncy = dy * ah + cy;
            float nw = expf(dw) * aw, nh = expf(dh) * ah;
            float x1 = ncx - 0.5f * nw, y1 = ncy - 0.5f * nh;
            float x2 = ncx + 0.5f * nw, y2 = ncy + 0.5f * nh;
            x1 = fminf(fmaxf(x1, 0.f), (float)(W * 16));
            x2 = fminf(fmaxf(x2, 0.f), (float)(W * 16));
            y1 = fminf(fmaxf(y1, 0.f), (float)(H * 16));
            y2 = fminf(fmaxf(y2, 0.f), (float)(H * 16));
            float4* bp = reinterpret_cast<float4*>(boxes);
            bp[idx] = make_float4(x1, y1, x2, y2);
        }
        __syncthreads();
    }
}

// partial stable-descending rank counts over a j-slice. grid (67, 8)
static constexpr int JSL = 2144;  // slice size (mult of 4)
__global__ __launch_bounds__(256) void k_rank_part(const float* __restrict__ fg,
                                                   int* __restrict__ cntb) {
    __shared__ float4 tile[256];
    int t = threadIdx.x;
    int i = blockIdx.x * 256 + t;
    int j0 = blockIdx.y * JSL;
    int j1 = min(NBOX, j0 + JSL);
    float my = (i < NBOX) ? fg[i] : 0.f;
    int cnt = 0;
    for (int base = j0; base < j1; base += 1024) {
        int j = base + t * 4;
        float4 v = make_float4(-3.4e38f, -3.4e38f, -3.4e38f, -3.4e38f);
        if (j + 3 < j1) {
            v = *reinterpret_cast<const float4*>(fg + j);
        } else {
            if (j < j1) v.x = fg[j];
            if (j + 1 < j1) v.y = fg[j + 1];
            if (j + 2 < j1) v.z = fg[j + 2];
            if (j + 3 < j1) v.w = fg[j + 3];
        }
        __syncthreads();
        tile[t] = v;
        __syncthreads();
        if (i < NBOX) {
            for (int u = 0; u < 256; ++u) {
                float4 s = tile[u];
                int jb = base + u * 4;
                cnt += (s.x > my) || (s.x == my && jb < i);
                cnt += (s.y > my) || (s.y == my && jb + 1 < i);
                cnt += (s.z > my) || (s.z == my && jb + 2 < i);
                cnt += (s.w > my) || (s.w == my && jb + 3 < i);
            }
        }
    }
    if (i < NBOX && cnt) atomicAdd(&cntb[i], cnt);
}

// scatter boxes to sorted order using rank counts
__global__ __launch_bounds__(256) void k_scatter(const int* __restrict__ cntb,
                                                 const float* __restrict__ boxes,
                                                 float* __restrict__ sboxes,
                                                 float* __restrict__ sarea) {
    int i = blockIdx.x * 256 + threadIdx.x;
    if (i >= NBOX) return;
    int c = cntb[i];
    float4 b = reinterpret_cast<const float4*>(boxes)[i];
    reinterpret_cast<float4*>(sboxes)[c] = b;
    sarea[c] = (b.z - b.x) * (b.w - b.y);
}

// NMS pair bitmask, row-major + diag 256-block bands (diagX memset 0 first).
__global__ __launch_bounds__(256) void k_maskfill(const float* __restrict__ sboxes,
                                                  const float* __restrict__ sarea,
                                                  U64* __restrict__ mask,
                                                  U64* __restrict__ diagX) {
    int w = blockIdx.y;
    int i0 = blockIdx.x * 256;
    if (w < (i0 >> 6)) return;
    __shared__ float4 sb[64];
    __shared__ float sa[64];
    int t = threadIdx.x;
    if (t < 64) {
        int j = w * 64 + t;
        if (j < NBOX) {
            sb[t] = reinterpret_cast<const float4*>(sboxes)[j];
            sa[t] = sarea[j];
        } else {
            sb[t] = make_float4(0.f, 0.f, 0.f, 0.f);
            sa[t] = 0.f;
        }
    }
    __syncthreads();
    int i = i0 + t;
    if (i >= NBOX || w < (i >> 6)) return;
    float4 bi = reinterpret_cast<const float4*>(sboxes)[i];
    float ai = sarea[i];
    U64 word = 0;
#pragma unroll 4
    for (int jb = 0; jb < 64; ++jb) {
        int j = w * 64 + jb;
        float4 bj = sb[jb];
        float xx1 = fmaxf(bi.x, bj.x), yy1 = fmaxf(bi.y, bj.y);
        float xx2 = fminf(bi.z, bj.z), yy2 = fminf(bi.w, bj.w);
        float inter = fmaxf(xx2 - xx1, 0.f) * fmaxf(yy2 - yy1, 0.f);
        float iou = inter / (ai + sa[jb] - inter);
        word |= ((U64)((iou > NMS_T) && (j > i))) << jb;
    }
    mask[(size_t)i * MSTRIDE + w] = word;
    int gi = i >> 8;
    int wl = w - gi * 4;
    if (wl >= 0 && wl < 4)
        diagX[(size_t)gi * 1024 + wl * 256 + (i & 255)] = word;
}

// ---- sweep v9: single wave, asm-pinned pipeline. Loads are inline-asm
// global_load_dwordx2 with "=v"-pinned results: compiler CANNOT sink or
// serialize them (v7/v8 failure mode: C loads sank to use -> 15K cyc/round).
#define GLOAD64(dst, addr) \
    asm volatile("global_load_dwordx2 %0, %1, off" : "=v"(dst) : "v"(addr))

#define VWAIT0() do { asm volatile("s_waitcnt vmcnt(0)" ::: "memory"); \
                      __builtin_amdgcn_sched_barrier(0); } while (0)

#define DVARS(P) U64 P##00, P##01, P##02, P##03, P##10, P##11, P##12, P##13, \
                     P##20, P##21, P##22, P##23, P##30, P##31, P##32, P##33

#define DISSUE(P, G) do { \
    const U64* _dp = diagX + (size_t)(G) * 1024 + lane; \
    GLOAD64(P##00, _dp +   0); GLOAD64(P##01, _dp +  64); GLOAD64(P##02, _dp + 128); GLOAD64(P##03, _dp + 192); \
    GLOAD64(P##10, _dp + 256); GLOAD64(P##11, _dp + 320); GLOAD64(P##12, _dp + 384); GLOAD64(P##13, _dp + 448); \
    GLOAD64(P##20, _dp + 512); GLOAD64(P##21, _dp + 576); GLOAD64(P##22, _dp + 640); GLOAD64(P##23, _dp + 704); \
    GLOAD64(P##30, _dp + 768); GLOAD64(P##31, _dp + 832); GLOAD64(P##32, _dp + 896); GLOAD64(P##33, _dp + 960); \
} while (0)

#define ZEROD(P) do { \
    P##00 = P##01 = P##02 = P##03 = P##10 = P##11 = P##12 = P##13 = 0; \
    P##20 = P##21 = P##22 = P##23 = P##30 = P##31 = P##32 = P##33 = 0; \
} while (0)

#define POPR(R) \
    int R; \
    do { \
        if (kk0) { int _i = (int)__builtin_ctzll(kk0); kk0 &= kk0 - 1; R = _i; } \
        else if (kk1) { int _i = (int)__builtin_ctzll(kk1); kk1 &= kk1 - 1; R = 64 + _i; } \
        else if (kk2) { int _i = (int)__builtin_ctzll(kk2); kk2 &= kk2 - 1; R = 128 + _i; } \
        else if (kk3) { int _i = (int)__builtin_ctzll(kk3); kk3 &= kk3 - 1; R = 192 + _i; } \
        else R = -1; \
    } while (0)

__global__ __launch_bounds__(64, 1) void k_sweep(const U64* __restrict__ mask,
                                                 const U64* __restrict__ diagX,
                                                 const float* __restrict__ sboxes,
                                                 float* __restrict__ rois_out,
                                                 float* __restrict__ keep_out) {
    int lane = threadIdx.x;
    U64 m0 = 0, m1 = 0, m2 = 0, m3 = 0, m4 = 0;
    unsigned base = 0;
    DVARS(c);
    DVARS(n);
    DISSUE(c, 0);
    VWAIT0();

    for (int g = 0; g < NG; ++g) {
        // (1) issue next group's diag band NOW (asm-pinned; completes by round end)
        if (g + 1 < NG) { DISSUE(n, g + 1); } else { ZEROD(n); }

        const int gbase = g * 256;
        // (2) resolve current group from registers (pure VALU)
        int rsel = g >> 4;
        U64 msel = (rsel == 0) ? m0 : (rsel == 1) ? m1 : (rsel == 2) ? m2 : (rsel == 3) ? m3 : m4;
        int lb = (g * 4) & 63;
        U64 mc0 = rdlane64(msel, lb), mc1 = rdlane64(msel, lb + 1);
        U64 mc2 = rdlane64(msel, lb + 2), mc3 = rdlane64(msel, lb + 3);
        U64 ns0 = ~mc0 & vmaskw(g * 4),     ns1 = ~mc1 & vmaskw(g * 4 + 1);
        U64 ns2 = ~mc2 & vmaskw(g * 4 + 2), ns3 = ~mc3 & vmaskw(g * 4 + 3);
        U64 k0 = 0, k1 = 0, k2 = 0, k3 = 0;
        while (ns0) {
            int i = (int)__builtin_ctzll(ns0);
            k0 |= 1ull << i;
            ns0 &= ~(rdlane64(c00, i) | (1ull << i));
            ns1 &= ~rdlane64(c10, i);
            ns2 &= ~rdlane64(c20, i);
            ns3 &= ~rdlane64(c30, i);
        }
        while (ns1) {
            int i = (int)__builtin_ctzll(ns1);
            k1 |= 1ull << i;
            ns1 &= ~(rdlane64(c11, i) | (1ull << i));
            ns2 &= ~rdlane64(c21, i);
            ns3 &= ~rdlane64(c31, i);
        }
        while (ns2) {
            int i = (int)__builtin_ctzll(ns2);
            k2 |= 1ull << i;
            ns2 &= ~(rdlane64(c22, i) | (1ull << i));
            ns3 &= ~rdlane64(c32, i);
        }
        while (ns3) {
            int i = (int)__builtin_ctzll(ns3);
            k3 |= 1ull << i;
            ns3 &= ~(rdlane64(c33, i) | (1ull << i));
        }
        unsigned p0 = (unsigned)__popcll(k0), p1 = (unsigned)__popcll(k1);
        unsigned p2 = (unsigned)__popcll(k2), p3 = (unsigned)__popcll(k3);
        U64 lmask = (1ull << lane) - 1ull;
        // (3) outputs
        if ((k0 >> lane) & 1) {
            unsigned dst = base + (unsigned)__popcll(k0 & lmask);
            reinterpret_cast<float4*>(rois_out)[dst] = reinterpret_cast<const float4*>(sboxes)[gbase + lane];
            keep_out[dst] = 1.0f;
        }
        if ((k1 >> lane) & 1) {
            unsigned dst = base + p0 + (unsigned)__popcll(k1 & lmask);
            reinterpret_cast<float4*>(rois_out)[dst] = reinterpret_cast<const float4*>(sboxes)[gbase + 64 + lane];
            keep_out[dst] = 1.0f;
        }
        if ((k2 >> lane) & 1) {
            unsigned dst = base + p0 + p1 + (unsigned)__popcll(k2 & lmask);
            reinterpret_cast<float4*>(rois_out)[dst] = reinterpret_cast<const float4*>(sboxes)[gbase + 128 + lane];
            keep_out[dst] = 1.0f;
        }
        if ((k3 >> lane) & 1) {
            unsigned dst = base + p0 + p1 + p2 + (unsigned)__popcll(k3 & lmask);
            reinterpret_cast<float4*>(rois_out)[dst] = reinterpret_cast<const float4*>(sboxes)[gbase + 192 + lane];
            keep_out[dst] = 1.0f;
        }
        base += p0 + p1 + p2 + p3;

        // (4) far-OR: batches of <=4 kept rows, asm-pinned loads, one wait/batch
        const int wmin = g * 4 + 4;
        const bool gw0 = (lane >= wmin);
        const bool gw1 = (64 + lane >= wmin);
        const bool gw2 = (128 + lane >= wmin);
        const bool gw3 = (192 + lane >= wmin);
        const bool gw4 = (256 + lane >= wmin) && (256 + lane < NW);
        U64 kk0 = k0, kk1 = k1, kk2 = k2, kk3 = k3;
        bool any = (kk0 | kk1 | kk2 | kk3) != 0;
        while (kk0 | kk1 | kk2 | kk3) {
            POPR(ra); POPR(rb); POPR(rc); POPR(rd);
            if (rb < 0) rb = ra;
            if (rc < 0) rc = ra;
            if (rd < 0) rd = ra;
            const U64* qa = mask + (size_t)(gbase + ra) * MSTRIDE + lane;
            const U64* qb = mask + (size_t)(gbase + rb) * MSTRIDE + lane;
            const U64* qc = mask + (size_t)(gbase + rc) * MSTRIDE + lane;
            const U64* qd = mask + (size_t)(gbase + rd) * MSTRIDE + lane;
            U64 va0, va1, va2, va3, va4, vb0, vb1, vb2, vb3, vb4;
            U64 vc0, vc1, vc2, vc3, vc4, vd0, vd1, vd2, vd3, vd4;
            GLOAD64(va0, qa);       GLOAD64(va1, qa + 64);  GLOAD64(va2, qa + 128);
            GLOAD64(va3, qa + 192); GLOAD64(va4, qa + 256);
            GLOAD64(vb0, qb);       GLOAD64(vb1, qb + 64);  GLOAD64(vb2, qb + 128);
            GLOAD64(vb3, qb + 192); GLOAD64(vb4, qb + 256);
            GLOAD64(vc0, qc);       GLOAD64(vc1, qc + 64);  GLOAD64(vc2, qc + 128);
            GLOAD64(vc3, qc + 192); GLOAD64(vc4, qc + 256);
            GLOAD64(vd0, qd);       GLOAD64(vd1, qd + 64);  GLOAD64(vd2, qd + 128);
            GLOAD64(vd3, qd + 192); GLOAD64(vd4, qd + 256);
            VWAIT0();   // also covers n-band loads (same round boundary)
            if (gw0) m0 |= va0 | vb0 | vc0 | vd0;
            if (gw1) m1 |= va1 | vb1 | vc1 | vd1;
            if (gw2) m2 |= va2 | vb2 | vc2 | vd2;
            if (gw3) m3 |= va3 | vb3 | vc3 | vd3;
            if (gw4) m4 |= va4 | vb4 | vc4 | vd4;
        }
        if (!any) VWAIT0();   // drain n-band loads before next resolve

        // (5) advance diag double-buffer (register copies)
        c00 = n00; c01 = n01; c02 = n02; c03 = n03;
        c10 = n10; c11 = n11; c12 = n12; c13 = n13;
        c20 = n20; c21 = n21; c22 = n22; c23 = n23;
        c30 = n30; c31 = n31; c32 = n32; c33 = n33;
    }
}

// ---------------- launch ----------------
extern "C" void kernel_launch(void* const* d_in, const int* in_sizes, int n_in,
                              void* d_out, int out_size, void* d_ws, size_t ws_size,
                              hipStream_t stream) {
    const float* fm      = (const float*)d_in[0];
    const float* conv_w  = (const float*)d_in[2];
    const float* conv_b  = (const float*)d_in[3];
    const float* score_w = (const float*)d_in[4];
    const float* score_b = (const float*)d_in[5];
    const float* loc_w   = (const float*)d_in[6];
    const float* loc_b   = (const float*)d_in[7];

    float* out = (float*)d_out;
    float* rois_out  = out;
    float* keep_out  = out + NBOX * 4;
    float* anch_out  = out + NBOX * 5;
    float* loc_out   = out + NBOX * 9;
    float* score_out = out + NBOX * 13;

    if (ws_size < WS_NEED) {
        k_sentinel<<<(out_size + 255) / 256, 256, 0, stream>>>(out, out_size);
        return;
    }

    char* ws = (char*)d_ws;
    float* in_tT   = (float*)(ws + OFF_INT);
    float* w2      = (float*)(ws + OFF_WT);
    float* partial = (float*)(ws + OFF_PART);
    U64*   mask    = (U64*)(ws + OFF_MASK);
    U64*   diagX   = (U64*)(ws + OFF_DIAG);
    float* mid     = (float*)(ws + OFF_MID);
    float* fg      = (float*)(ws + OFF_FG);
    float* boxes   = (float*)(ws + OFF_BOX);
    float* sboxes  = (float*)(ws + OFF_SBOX);
    float* sarea   = (float*)(ws + OFF_SAREA);
    int*   cntb    = (int*)(ws + OFF_CNT);

    hipMemsetAsync(in_tT, 0, SZ_INT, stream);
    k_in_t<<<(CIN * H * W + 255) / 256, 256, 0, stream>>>(fm, in_tT);
    k_w_t<<<(CMID * CIN * 9 + 255) / 256, 256, 0, stream>>>(conv_w, w2);
    k_conv<<<504, 256, 0, stream>>>(in_tT, w2, partial);
    k_reduce<<<P, 256, 0, stream>>>(partial, conv_b, mid);
    k_heads<<<(P + 15) / 16, 256, 0, stream>>>(mid, score_w, score_b, loc_w, loc_b,
                                               score_out, loc_out, anch_out, fg, boxes);
    hipMemsetAsync(cntb, 0, NBOX * 4, stream);
    k_rank_part<<<dim3((NBOX + 255) / 256, 8), 256, 0, stream>>>(fg, cntb);
    k_scatter<<<(NBOX + 255) / 256, 256, 0, stream>>>(cntb, boxes, sboxes, sarea);
    hipMemsetAsync(rois_out, 0, (size_t)NBOX * 5 * 4, stream);  // rois_out + keep
    hipMemsetAsync(diagX, 0, SZ_DIAG, stream);
    k_maskfill<<<dim3((NBOX + 255) / 256, NW), 256, 0, stream>>>(sboxes, sarea, mask, diagX);
    k_sweep<<<1, 64, 0, stream>>>(mask, diagX, sboxes, rois_out, keep_out);
}

// Round 14
// 752.055 us; speedup vs baseline: 1.3239x; 1.0167x over previous
//
#include <hip/hip_runtime.h>
#include <cstdint>

#define U64 unsigned long long

static constexpr int H = 38, W = 50, P = 1900;        // feature map
static constexpr int CIN = 2048, CMID = 256;
static constexpr int NA = 9, NBOX = 17100;            // 1900*9
static constexpr int HP = 40, WP = 52, QP = HP * WP;  // padded positions (2080)
static constexpr int TPITCH = 2084;                   // in_tT row pitch (floats), mult of 4
static constexpr int KS = 7;                          // split-K over cin
static constexpr int NW = 268;                        // u64 words covering NBOX bits
static constexpr int MSTRIDE = 272;                   // mask row stride (words)
static constexpr int NG = 67;                         // 256-box groups
static constexpr float NMS_T = 0.5f;
static constexpr int QTILE = 256;

// ---------------- ws layout (bytes) ----------------
static constexpr size_t SZ_INT  = (size_t)CIN * TPITCH * 4;   // 17,072,128
static constexpr size_t SZ_WT   = (size_t)9 * CIN * CMID * 4; // 18,874,368
static constexpr size_t SZ_PART = (size_t)KS * P * CMID * 4;  // 13,619,200
static constexpr size_t OFF_INT  = 0;
static constexpr size_t OFF_WT   = OFF_INT + SZ_INT;
static constexpr size_t OFF_PART = OFF_WT + SZ_WT;
static constexpr size_t REGA     = OFF_PART + SZ_PART;        // 49,565,696
// region A overlay (dead after k_reduce): mask + diag 256-blocks
static constexpr size_t OFF_MASK = 0;                          // mask [NBOX][MSTRIDE] (37.2 MB)
static constexpr size_t SZ_MASK  = (size_t)NBOX * MSTRIDE * 8; // 37,209,600
static constexpr size_t OFF_DIAG = SZ_MASK;                    // diagX [67][4][4][64] u64 (549 KB)
static constexpr size_t SZ_DIAG  = (size_t)NG * 1024 * 8;      // 548,864
static constexpr size_t OFF_MID  = REGA;
static constexpr size_t OFF_FG   = OFF_MID + 1945600;
static constexpr size_t OFF_BOX  = OFF_FG + 68608;
static constexpr size_t OFF_SBOX = OFF_BOX + 273664;
static constexpr size_t OFF_SAREA= OFF_SBOX + 273664;
static constexpr size_t OFF_CNT  = OFF_SAREA + 68608;
static constexpr size_t WS_NEED  = OFF_CNT + 68608;            // ~52.26 MB (unchanged)

__device__ __forceinline__ U64 rdlane64(U64 v, int l) {
    unsigned lo = (unsigned)__builtin_amdgcn_readlane((int)(unsigned)(v & 0xffffffffull), l);
    unsigned hi = (unsigned)__builtin_amdgcn_readlane((int)(unsigned)(v >> 32), l);
    return ((U64)hi << 32) | (U64)lo;
}

__device__ __forceinline__ U64 vmaskw(int wg) {
    int rem = NBOX - wg * 64;
    if (rem >= 64) return ~0ull;
    if (rem <= 0) return 0ull;
    return (1ull << rem) - 1ull;
}

// ---------------- kernels ----------------

__global__ __launch_bounds__(256) void k_sentinel(float* out, int n) {
    int i = blockIdx.x * 256 + threadIdx.x;
    if (i < n) out[i] = 1.2345678e8f;
}

// feature_map [CIN][H][W] -> in_tT [CIN][TPITCH] (padded image rows; memset first)
__global__ __launch_bounds__(256) void k_in_t(const float* __restrict__ fm, float* __restrict__ in_tT) {
    int idx = blockIdx.x * 256 + threadIdx.x;
    if (idx >= CIN * (H * W)) return;
    int ci = idx / (H * W), hw = idx - ci * (H * W);
    int h = hw / W, w = hw - h * W;
    in_tT[(size_t)ci * TPITCH + (h + 1) * WP + 1 + w] = fm[idx];
}

// conv_w [CMID][CIN][3][3] -> w2 [y(8)][sub(4)][ci(2048)][k(9)][c(8)]
__global__ __launch_bounds__(256) void k_w_t(const float* __restrict__ cw, float* __restrict__ w2) {
    int idx = blockIdx.x * 256 + threadIdx.x;
    if (idx >= CMID * CIN * 9) return;
    int co = idx / (CIN * 9);
    int rem = idx - co * (CIN * 9);
    int ci = rem / 9, k = rem - ci * 9;
    w2[((size_t)(co >> 3) * CIN + ci) * 72 + k * 8 + (co & 7)] = cw[idx];
}

// 3x3 conv, split-K. grid 504 = 9 qtiles x 8 cout-groups x 7 z (XCD-swizzled).
// PLAIN LDS layout: b128 reads of consecutive quads are conflict-free (each
// 8-lane phase hits 32 distinct banks). Round-12's skew caused 3.5e7 conflicts.
__global__ __launch_bounds__(256, 2) void k_conv(const float* __restrict__ in_tT,
                                                 const float* __restrict__ w2,
                                                 float* __restrict__ partial) {
    __shared__ float4 s_in4[16 * 92];    // 16 ci x 92 quads, plain (23.5 KB)
    int t = threadIdx.x;
    int lane = t & 63;
    int sub = __builtin_amdgcn_readfirstlane(t >> 6);   // wave-uniform SGPR

    int raw = blockIdx.x;
    int xcd = raw & 7, i0 = raw >> 3;
    int L = xcd * 63 + i0;          // 504 = 8*63, bijective
    int z = L / 72;
    int r0 = L - z * 72;
    int bx = r0 % 9, by = r0 / 9;
    int q0 = bx * QTILE;
    int cout0 = by * 32;
    int cin0 = (z <= 1) ? 304 * z : 608 + 288 * (z - 2);   // 304,304,288x5
    int cin1 = cin0 + ((z <= 1) ? 304 : 288);

    float acc[4][8];
#pragma unroll
    for (int j = 0; j < 4; ++j)
#pragma unroll
        for (int c = 0; c < 8; ++c) acc[j][c] = 0.f;

    const float* wbase = w2 + (size_t)(by * 4 + sub) * CIN * 72;

    for (int c0 = cin0; c0 < cin1; c0 += 16) {
        for (int idx = t; idx < 16 * 92; idx += 256) {
            int r = idx / 92, j = idx - r * 92;
            int qf = q0 - 56 + 4 * j;
            float4 v = make_float4(0.f, 0.f, 0.f, 0.f);
            if (qf >= 0 && qf <= 2080)
                v = *reinterpret_cast<const float4*>(in_tT + (size_t)(c0 + r) * TPITCH + qf);
            s_in4[r * 92 + j] = v;
        }
        __syncthreads();
#pragma unroll 1
        for (int r = 0; r < 16; ++r) {
            const float4* row4 = s_in4 + r * 92;
            const float4* w4 = reinterpret_cast<const float4*>(wbase + (size_t)(c0 + r) * 72);
#pragma unroll
            for (int dy = 0; dy < 3; ++dy) {
                int v0 = lane + 13 * dy;
                float4 F0 = row4[v0];
                float4 F1 = row4[v0 + 1];
                float4 F2 = row4[v0 + 2];
                float F[12] = {F0.x, F0.y, F0.z, F0.w, F1.x, F1.y, F1.z, F1.w,
                               F2.x, F2.y, F2.z, F2.w};
#pragma unroll
                for (int dxi = 0; dxi < 3; ++dxi) {
                    int k = dy * 3 + dxi;
                    float4 wa = w4[k * 2], wb = w4[k * 2 + 1];
                    float wv[8] = {wa.x, wa.y, wa.z, wa.w, wb.x, wb.y, wb.z, wb.w};
#pragma unroll
                    for (int jj = 0; jj < 4; ++jj) {
                        float iv = F[jj + dxi + 3];
#pragma unroll
                        for (int c = 0; c < 8; ++c) acc[jj][c] += iv * wv[c];
                    }
                }
            }
        }
        __syncthreads();
    }
    float* part = partial + (size_t)z * P * CMID;
#pragma unroll
    for (int jj = 0; jj < 4; ++jj) {
        int q = q0 + 4 * lane + jj;
        if (q < QP) {
            int hp = q / WP, wp_ = q - hp * WP;
            if (hp >= 1 && hp <= H && wp_ >= 1 && wp_ <= W) {
                int p = (hp - 1) * W + (wp_ - 1);
                float* dst = part + (size_t)p * CMID + cout0 + sub * 8;
                float4* d4 = reinterpret_cast<float4*>(dst);
                d4[0] = make_float4(acc[jj][0], acc[jj][1], acc[jj][2], acc[jj][3]);
                d4[1] = make_float4(acc[jj][4], acc[jj][5], acc[jj][6], acc[jj][7]);
            }
        }
    }
}

// sum partials + bias + relu -> mid [P][CMID]
__global__ __launch_bounds__(256) void k_reduce(const float* __restrict__ partial,
                                                const float* __restrict__ bias,
                                                float* __restrict__ mid) {
    int p = blockIdx.x, c = threadIdx.x;
    float s = bias[c];
    for (int ks = 0; ks < KS; ++ks) s += partial[(size_t)ks * P * CMID + (size_t)p * CMID + c];
    mid[(size_t)p * CMID + c] = fmaxf(s, 0.f);
}

// 1x1 heads + softmax + anchors + loc2bbox + clip. 16 positions per block (4 reps).
__global__ __launch_bounds__(256) void k_heads(const float* __restrict__ mid,
                                               const float* __restrict__ score_w,
                                               const float* __restrict__ score_b,
                                               const float* __restrict__ loc_w,
                                               const float* __restrict__ loc_b,
                                               float* __restrict__ score_out,
                                               float* __restrict__ loc_out,
                                               float* __restrict__ anch_out,
                                               float* __restrict__ fg,
                                               float* __restrict__ boxes) {
    __shared__ float wl[256][56];
    __shared__ float bias[56];
    __shared__ float dots[4][64];
    int t = threadIdx.x;
    for (int idx = t; idx < 18 * 256; idx += 256) {
        int c = idx >> 8, i = idx & 255;
        wl[i][c] = score_w[idx];
    }
    for (int idx = t; idx < 36 * 256; idx += 256) {
        int c = idx >> 8, i = idx & 255;
        wl[i][18 + c] = loc_w[idx];
    }
    if (t < 18) bias[t] = score_b[t];
    else if (t < 54) bias[t] = loc_b[t - 18];
    __syncthreads();

    int pl = t >> 6, c = t & 63;
    for (int rep = 0; rep < 4; ++rep) {
        int p = blockIdx.x * 16 + rep * 4 + pl;
        if (c < 54 && p < P) {
            float d = bias[c];
            const float4* mp = reinterpret_cast<const float4*>(mid + (size_t)p * CMID);
            for (int i4 = 0; i4 < 64; ++i4) {
                float4 m4 = mp[i4];
                int i = i4 * 4;
                d += m4.x * wl[i][c] + m4.y * wl[i + 1][c] + m4.z * wl[i + 2][c] + m4.w * wl[i + 3][c];
            }
            dots[pl][c] = d;
        }
        __syncthreads();
        if (c < NA && p < P) {
            int a = c;
            int idx = p * NA + a;
            float l0 = dots[pl][2 * a], l1 = dots[pl][2 * a + 1];
            float mx = fmaxf(l0, l1);
            float e0 = expf(l0 - mx), e1 = expf(l1 - mx);
            float den = e0 + e1;
            float s0 = e0 / den, s1 = e1 / den;
            score_out[(size_t)idx * 2 + 0] = s0;
            score_out[(size_t)idx * 2 + 1] = s1;
            fg[idx] = s1;
            float dx = dots[pl][18 + 4 * a + 0];
            float dy = dots[pl][18 + 4 * a + 1];
            float dw = dots[pl][18 + 4 * a + 2];
            float dh = dots[pl][18 + 4 * a + 3];
            loc_out[(size_t)idx * 4 + 0] = dx;
            loc_out[(size_t)idx * 4 + 1] = dy;
            loc_out[(size_t)idx * 4 + 2] = dw;
            loc_out[(size_t)idx * 4 + 3] = dh;
            int hh = p / W, ww = p % W;
            const double scales[3] = {8.0, 16.0, 32.0};
            const double ratios[3] = {0.5, 1.0, 2.0};
            double s = scales[a / 3], r = ratios[a % 3];
            double wb2 = 16.0 * s * sqrt(r);
            double hb = wb2 / r;
            double xmin = 8.0 - wb2 / 2.0, ymin = 8.0 - hb / 2.0;
            float b0 = (float)xmin, b1 = (float)ymin;
            float b2 = (float)(xmin + wb2), b3 = (float)(ymin + hb);
            float gx = (float)(ww * 16), gy = (float)(hh * 16);
            float a0 = gx + b0, a1 = gy + b1, a2 = gx + b2, a3 = gy + b3;
            anch_out[(size_t)idx * 4 + 0] = a0;
            anch_out[(size_t)idx * 4 + 1] = a1;
            anch_out[(size_t)idx * 4 + 2] = a2;
            anch_out[(size_t)idx * 4 + 3] = a3;
            float aw = a2 - a0, ah = a3 - a1;
            float cx = a0 + 0.5f * aw, cy = a1 + 0.5f * ah;
            float ncx = dx * aw + cx, ncy = dy * ah + cy;
            float nw = expf(dw) * aw, nh = expf(dh) * ah;
            float x1 = ncx - 0.5f * nw, y1 = ncy - 0.5f * nh;
            float x2 = ncx + 0.5f * nw, y2 = ncy + 0.5f * nh;
            x1 = fminf(fmaxf(x1, 0.f), (float)(W * 16));
            x2 = fminf(fmaxf(x2, 0.f), (float)(W * 16));
            y1 = fminf(fmaxf(y1, 0.f), (float)(H * 16));
            y2 = fminf(fmaxf(y2, 0.f), (float)(H * 16));
            float4* bp = reinterpret_cast<float4*>(boxes);
            bp[idx] = make_float4(x1, y1, x2, y2);
        }
        __syncthreads();
    }
}

// partial stable-descending rank counts over a j-slice. grid (67, 8)
static constexpr int JSL = 2144;  // slice size (mult of 4)
__global__ __launch_bounds__(256) void k_rank_part(const float* __restrict__ fg,
                                                   int* __restrict__ cntb) {
    __shared__ float4 tile[256];
    int t = threadIdx.x;
    int i = blockIdx.x * 256 + t;
    int j0 = blockIdx.y * JSL;
    int j1 = min(NBOX, j0 + JSL);
    float my = (i < NBOX) ? fg[i] : 0.f;
    int cnt = 0;
    for (int base = j0; base < j1; base += 1024) {
        int j = base + t * 4;
        float4 v = make_float4(-3.4e38f, -3.4e38f, -3.4e38f, -3.4e38f);
        if (j + 3 < j1) {
            v = *reinterpret_cast<const float4*>(fg + j);
        } else {
            if (j < j1) v.x = fg[j];
            if (j + 1 < j1) v.y = fg[j + 1];
            if (j + 2 < j1) v.z = fg[j + 2];
            if (j + 3 < j1) v.w = fg[j + 3];
        }
        __syncthreads();
        tile[t] = v;
        __syncthreads();
        if (i < NBOX) {
            for (int u = 0; u < 256; ++u) {
                float4 s = tile[u];
                int jb = base + u * 4;
                cnt += (s.x > my) || (s.x == my && jb < i);
                cnt += (s.y > my) || (s.y == my && jb + 1 < i);
                cnt += (s.z > my) || (s.z == my && jb + 2 < i);
                cnt += (s.w > my) || (s.w == my && jb + 3 < i);
            }
        }
    }
    if (i < NBOX && cnt) atomicAdd(&cntb[i], cnt);
}

// scatter boxes to sorted order using rank counts
__global__ __launch_bounds__(256) void k_scatter(const int* __restrict__ cntb,
                                                 const float* __restrict__ boxes,
                                                 float* __restrict__ sboxes,
                                                 float* __restrict__ sarea) {
    int i = blockIdx.x * 256 + threadIdx.x;
    if (i >= NBOX) return;
    int c = cntb[i];
    float4 b = reinterpret_cast<const float4*>(boxes)[i];
    reinterpret_cast<float4*>(sboxes)[c] = b;
    sarea[c] = (b.z - b.x) * (b.w - b.y);
}

// NMS pair bitmask, row-major + diag 256-block bands (diagX memset 0 first).
__global__ __launch_bounds__(256) void k_maskfill(const float* __restrict__ sboxes,
                                                  const float* __restrict__ sarea,
                                                  U64* __restrict__ mask,
                                                  U64* __restrict__ diagX) {
    int w = blockIdx.y;
    int i0 = blockIdx.x * 256;
    if (w < (i0 >> 6)) return;
    __shared__ float4 sb[64];
    __shared__ float sa[64];
    int t = threadIdx.x;
    if (t < 64) {
        int j = w * 64 + t;
        if (j < NBOX) {
            sb[t] = reinterpret_cast<const float4*>(sboxes)[j];
            sa[t] = sarea[j];
        } else {
            sb[t] = make_float4(0.f, 0.f, 0.f, 0.f);
            sa[t] = 0.f;
        }
    }
    __syncthreads();
    int i = i0 + t;
    if (i >= NBOX || w < (i >> 6)) return;
    float4 bi = reinterpret_cast<const float4*>(sboxes)[i];
    float ai = sarea[i];
    U64 word = 0;
#pragma unroll 4
    for (int jb = 0; jb < 64; ++jb) {
        int j = w * 64 + jb;
        float4 bj = sb[jb];
        float xx1 = fmaxf(bi.x, bj.x), yy1 = fmaxf(bi.y, bj.y);
        float xx2 = fminf(bi.z, bj.z), yy2 = fminf(bi.w, bj.w);
        float inter = fmaxf(xx2 - xx1, 0.f) * fmaxf(yy2 - yy1, 0.f);
        float iou = inter / (ai + sa[jb] - inter);
        word |= ((U64)((iou > NMS_T) && (j > i))) << jb;
    }
    mask[(size_t)i * MSTRIDE + w] = word;
    int gi = i >> 8;
    int wl = w - gi * 4;
    if (wl >= 0 && wl < 4)
        diagX[(size_t)gi * 1024 + wl * 256 + (i & 255)] = word;
}

// ---- sweep v9: single wave, asm-pinned pipeline (round-12, unchanged).
#define GLOAD64(dst, addr) \
    asm volatile("global_load_dwordx2 %0, %1, off" : "=v"(dst) : "v"(addr))

#define VWAIT0() do { asm volatile("s_waitcnt vmcnt(0)" ::: "memory"); \
                      __builtin_amdgcn_sched_barrier(0); } while (0)

#define DVARS(P) U64 P##00, P##01, P##02, P##03, P##10, P##11, P##12, P##13, \
                     P##20, P##21, P##22, P##23, P##30, P##31, P##32, P##33

#define DISSUE(P, G) do { \
    const U64* _dp = diagX + (size_t)(G) * 1024 + lane; \
    GLOAD64(P##00, _dp +   0); GLOAD64(P##01, _dp +  64); GLOAD64(P##02, _dp + 128); GLOAD64(P##03, _dp + 192); \
    GLOAD64(P##10, _dp + 256); GLOAD64(P##11, _dp + 320); GLOAD64(P##12, _dp + 384); GLOAD64(P##13, _dp + 448); \
    GLOAD64(P##20, _dp + 512); GLOAD64(P##21, _dp + 576); GLOAD64(P##22, _dp + 640); GLOAD64(P##23, _dp + 704); \
    GLOAD64(P##30, _dp + 768); GLOAD64(P##31, _dp + 832); GLOAD64(P##32, _dp + 896); GLOAD64(P##33, _dp + 960); \
} while (0)

#define ZEROD(P) do { \
    P##00 = P##01 = P##02 = P##03 = P##10 = P##11 = P##12 = P##13 = 0; \
    P##20 = P##21 = P##22 = P##23 = P##30 = P##31 = P##32 = P##33 = 0; \
} while (0)

#define POPR(R) \
    int R; \
    do { \
        if (kk0) { int _i = (int)__builtin_ctzll(kk0); kk0 &= kk0 - 1; R = _i; } \
        else if (kk1) { int _i = (int)__builtin_ctzll(kk1); kk1 &= kk1 - 1; R = 64 + _i; } \
        else if (kk2) { int _i = (int)__builtin_ctzll(kk2); kk2 &= kk2 - 1; R = 128 + _i; } \
        else if (kk3) { int _i = (int)__builtin_ctzll(kk3); kk3 &= kk3 - 1; R = 192 + _i; } \
        else R = -1; \
    } while (0)

__global__ __launch_bounds__(64, 1) void k_sweep(const U64* __restrict__ mask,
                                                 const U64* __restrict__ diagX,
                                                 const float* __restrict__ sboxes,
                                                 float* __restrict__ rois_out,
                                                 float* __restrict__ keep_out) {
    int lane = threadIdx.x;
    U64 m0 = 0, m1 = 0, m2 = 0, m3 = 0, m4 = 0;
    unsigned base = 0;
    DVARS(c);
    DVARS(n);
    DISSUE(c, 0);
    VWAIT0();

    for (int g = 0; g < NG; ++g) {
        if (g + 1 < NG) { DISSUE(n, g + 1); } else { ZEROD(n); }

        const int gbase = g * 256;
        int rsel = g >> 4;
        U64 msel = (rsel == 0) ? m0 : (rsel == 1) ? m1 : (rsel == 2) ? m2 : (rsel == 3) ? m3 : m4;
        int lb = (g * 4) & 63;
        U64 mc0 = rdlane64(msel, lb), mc1 = rdlane64(msel, lb + 1);
        U64 mc2 = rdlane64(msel, lb + 2), mc3 = rdlane64(msel, lb + 3);
        U64 ns0 = ~mc0 & vmaskw(g * 4),     ns1 = ~mc1 & vmaskw(g * 4 + 1);
        U64 ns2 = ~mc2 & vmaskw(g * 4 + 2), ns3 = ~mc3 & vmaskw(g * 4 + 3);
        U64 k0 = 0, k1 = 0, k2 = 0, k3 = 0;
        while (ns0) {
            int i = (int)__builtin_ctzll(ns0);
            k0 |= 1ull << i;
            ns0 &= ~(rdlane64(c00, i) | (1ull << i));
            ns1 &= ~rdlane64(c10, i);
            ns2 &= ~rdlane64(c20, i);
            ns3 &= ~rdlane64(c30, i);
        }
        while (ns1) {
            int i = (int)__builtin_ctzll(ns1);
            k1 |= 1ull << i;
            ns1 &= ~(rdlane64(c11, i) | (1ull << i));
            ns2 &= ~rdlane64(c21, i);
            ns3 &= ~rdlane64(c31, i);
        }
        while (ns2) {
            int i = (int)__builtin_ctzll(ns2);
            k2 |= 1ull << i;
            ns2 &= ~(rdlane64(c22, i) | (1ull << i));
            ns3 &= ~rdlane64(c32, i);
        }
        while (ns3) {
            int i = (int)__builtin_ctzll(ns3);
            k3 |= 1ull << i;
            ns3 &= ~(rdlane64(c33, i) | (1ull << i));
        }
        unsigned p0 = (unsigned)__popcll(k0), p1 = (unsigned)__popcll(k1);
        unsigned p2 = (unsigned)__popcll(k2), p3 = (unsigned)__popcll(k3);
        U64 lmask = (1ull << lane) - 1ull;
        if ((k0 >> lane) & 1) {
            unsigned dst = base + (unsigned)__popcll(k0 & lmask);
            reinterpret_cast<float4*>(rois_out)[dst] = reinterpret_cast<const float4*>(sboxes)[gbase + lane];
            keep_out[dst] = 1.0f;
        }
        if ((k1 >> lane) & 1) {
            unsigned dst = base + p0 + (unsigned)__popcll(k1 & lmask);
            reinterpret_cast<float4*>(rois_out)[dst] = reinterpret_cast<const float4*>(sboxes)[gbase + 64 + lane];
            keep_out[dst] = 1.0f;
        }
        if ((k2 >> lane) & 1) {
            unsigned dst = base + p0 + p1 + (unsigned)__popcll(k2 & lmask);
            reinterpret_cast<float4*>(rois_out)[dst] = reinterpret_cast<const float4*>(sboxes)[gbase + 128 + lane];
            keep_out[dst] = 1.0f;
        }
        if ((k3 >> lane) & 1) {
            unsigned dst = base + p0 + p1 + p2 + (unsigned)__popcll(k3 & lmask);
            reinterpret_cast<float4*>(rois_out)[dst] = reinterpret_cast<const float4*>(sboxes)[gbase + 192 + lane];
            keep_out[dst] = 1.0f;
        }
        base += p0 + p1 + p2 + p3;

        const int wmin = g * 4 + 4;
        const bool gw0 = (lane >= wmin);
        const bool gw1 = (64 + lane >= wmin);
        const bool gw2 = (128 + lane >= wmin);
        const bool gw3 = (192 + lane >= wmin);
        const bool gw4 = (256 + lane >= wmin) && (256 + lane < NW);
        U64 kk0 = k0, kk1 = k1, kk2 = k2, kk3 = k3;
        bool any = (kk0 | kk1 | kk2 | kk3) != 0;
        while (kk0 | kk1 | kk2 | kk3) {
            POPR(ra); POPR(rb); POPR(rc); POPR(rd);
            if (rb < 0) rb = ra;
            if (rc < 0) rc = ra;
            if (rd < 0) rd = ra;
            const U64* qa = mask + (size_t)(gbase + ra) * MSTRIDE + lane;
            const U64* qb = mask + (size_t)(gbase + rb) * MSTRIDE + lane;
            const U64* qc = mask + (size_t)(gbase + rc) * MSTRIDE + lane;
            const U64* qd = mask + (size_t)(gbase + rd) * MSTRIDE + lane;
            U64 va0, va1, va2, va3, va4, vb0, vb1, vb2, vb3, vb4;
            U64 vc0, vc1, vc2, vc3, vc4, vd0, vd1, vd2, vd3, vd4;
            GLOAD64(va0, qa);       GLOAD64(va1, qa + 64);  GLOAD64(va2, qa + 128);
            GLOAD64(va3, qa + 192); GLOAD64(va4, qa + 256);
            GLOAD64(vb0, qb);       GLOAD64(vb1, qb + 64);  GLOAD64(vb2, qb + 128);
            GLOAD64(vb3, qb + 192); GLOAD64(vb4, qb + 256);
            GLOAD64(vc0, qc);       GLOAD64(vc1, qc + 64);  GLOAD64(vc2, qc + 128);
            GLOAD64(vc3, qc + 192); GLOAD64(vc4, qc + 256);
            GLOAD64(vd0, qd);       GLOAD64(vd1, qd + 64);  GLOAD64(vd2, qd + 128);
            GLOAD64(vd3, qd + 192); GLOAD64(vd4, qd + 256);
            VWAIT0();
            if (gw0) m0 |= va0 | vb0 | vc0 | vd0;
            if (gw1) m1 |= va1 | vb1 | vc1 | vd1;
            if (gw2) m2 |= va2 | vb2 | vc2 | vd2;
            if (gw3) m3 |= va3 | vb3 | vc3 | vd3;
            if (gw4) m4 |= va4 | vb4 | vc4 | vd4;
        }
        if (!any) VWAIT0();

        c00 = n00; c01 = n01; c02 = n02; c03 = n03;
        c10 = n10; c11 = n11; c12 = n12; c13 = n13;
        c20 = n20; c21 = n21; c22 = n22; c23 = n23;
        c30 = n30; c31 = n31; c32 = n32; c33 = n33;
    }
}

// ---------------- launch ----------------
extern "C" void kernel_launch(void* const* d_in, const int* in_sizes, int n_in,
                              void* d_out, int out_size, void* d_ws, size_t ws_size,
                              hipStream_t stream) {
    const float* fm      = (const float*)d_in[0];
    const float* conv_w  = (const float*)d_in[2];
    const float* conv_b  = (const float*)d_in[3];
    const float* score_w = (const float*)d_in[4];
    const float* score_b = (const float*)d_in[5];
    const float* loc_w   = (const float*)d_in[6];
    const float* loc_b   = (const float*)d_in[7];

    float* out = (float*)d_out;
    float* rois_out  = out;
    float* keep_out  = out + NBOX * 4;
    float* anch_out  = out + NBOX * 5;
    float* loc_out   = out + NBOX * 9;
    float* score_out = out + NBOX * 13;

    if (ws_size < WS_NEED) {
        k_sentinel<<<(out_size + 255) / 256, 256, 0, stream>>>(out, out_size);
        return;
    }

    char* ws = (char*)d_ws;
    float* in_tT   = (float*)(ws + OFF_INT);
    float* w2      = (float*)(ws + OFF_WT);
    float* partial = (float*)(ws + OFF_PART);
    U64*   mask    = (U64*)(ws + OFF_MASK);
    U64*   diagX   = (U64*)(ws + OFF_DIAG);
    float* mid     = (float*)(ws + OFF_MID);
    float* fg      = (float*)(ws + OFF_FG);
    float* boxes   = (float*)(ws + OFF_BOX);
    float* sboxes  = (float*)(ws + OFF_SBOX);
    float* sarea   = (float*)(ws + OFF_SAREA);
    int*   cntb    = (int*)(ws + OFF_CNT);

    hipMemsetAsync(in_tT, 0, SZ_INT, stream);
    k_in_t<<<(CIN * H * W + 255) / 256, 256, 0, stream>>>(fm, in_tT);
    k_w_t<<<(CMID * CIN * 9 + 255) / 256, 256, 0, stream>>>(conv_w, w2);
    k_conv<<<504, 256, 0, stream>>>(in_tT, w2, partial);
    k_reduce<<<P, 256, 0, stream>>>(partial, conv_b, mid);
    k_heads<<<(P + 15) / 16, 256, 0, stream>>>(mid, score_w, score_b, loc_w, loc_b,
                                               score_out, loc_out, anch_out, fg, boxes);
    hipMemsetAsync(cntb, 0, NBOX * 4, stream);
    k_rank_part<<<dim3((NBOX + 255) / 256, 8), 256, 0, stream>>>(fg, cntb);
    k_scatter<<<(NBOX + 255) / 256, 256, 0, stream>>>(cntb, boxes, sboxes, sarea);
    hipMemsetAsync(rois_out, 0, (size_t)NBOX * 5 * 4, stream);  // rois_out + keep
    hipMemsetAsync(diagX, 0, SZ_DIAG, stream);
    k_maskfill<<<dim3((NBOX + 255) / 256, NW), 256, 0, stream>>>(sboxes, sarea, mask, diagX);
    k_sweep<<<1, 64, 0, stream>>>(mask, diagX, sboxes, rois_out, keep_out);
}